// Round 4
// baseline (9216.879 us; speedup 1.0000x reference)
//
#include <hip/hip_runtime.h>
#include <hip/hip_bf16.h>
#include <stdint.h>

// Problem dims
#define BB 256
#define TT 512
#define EE 128
#define HH 256
#define MM (TT*BB)       // 131072 rows total
#define CT 64            // timesteps per chunk
#define NCH (TT/CT)      // 8 chunks
#define CROWS (CT*BB)    // 16384 rows per chunk

typedef __attribute__((ext_vector_type(8))) short bf16x8;
typedef __attribute__((ext_vector_type(4))) float f32x4;

__device__ __forceinline__ float bf2f(unsigned short u){
  union { unsigned int i; float f; } v; v.i = ((unsigned int)u) << 16; return v.f;
}
__device__ __forceinline__ unsigned short f2bf(float f){
  union { float f; unsigned int i; } v; v.f = f;
  unsigned int u = v.i;
  unsigned int r = (u + 0x7FFFu + ((u >> 16) & 1u)) >> 16;
  return (unsigned short)r;
}
__device__ __forceinline__ float sigm(float x){ return 1.f / (1.f + __expf(-x)); }
__device__ __forceinline__ float tanh_f(float x){
  float e2 = __expf(2.f * x);
  return 1.f - 2.f / (e2 + 1.f);
}

// -------- sentinel --------
__global__ void k_sentinel(unsigned short* out, float v){ out[threadIdx.x] = f2bf(v); }

// -------- dtype probe: is this float tensor fp32 (vs bf16)? --------
// bf16 of random normal/uniform data: no nonzero word has exp<0x60 or ==0xFF.
// fp32 viewed as u16: low halves are ~uniform -> ~19% of all words flagged.
__global__ void k_probe_f(const unsigned short* __restrict__ buf, int n,
                          unsigned* __restrict__ flagw){
  __shared__ int cnt;
  if (threadIdx.x == 0) cnt = 0;
  __syncthreads();
  int scanw = n < 4096 ? n : 4096;
  int bad = 0;
  for (int i = threadIdx.x; i < scanw; i += 256){
    unsigned short u = buf[i];
    unsigned e = (u >> 7) & 0xFF;
    if (u != 0 && (e < 0x60 || e == 0xFF)) bad++;
  }
  atomicAdd(&cnt, bad);
  __syncthreads();
  if (threadIdx.x == 0) *flagw = (cnt * 8 > scanw) ? 1u : 0u;
}

// -------- int width probe: int64 iff odd int32 words are (almost) all zero --------
__global__ void k_probe_i(const int* __restrict__ buf, int n, unsigned* __restrict__ flagw){
  __shared__ int cnt;
  if (threadIdx.x == 0) cnt = 0;
  __syncthreads();
  int scan = n < 1024 ? n : 1024;
  int nz = 0;
  for (int i = threadIdx.x; i < scan; i += 256)
    if ((i & 1) && buf[i] != 0) nz++;
  atomicAdd(&cnt, nz);
  __syncthreads();
  if (threadIdx.x == 0) *flagw = (cnt < 10) ? 1u : 0u;
}

// -------- convert a float tensor (fp32 or bf16 per flag) to bf16 dst --------
__global__ __launch_bounds__(256) void k_convert(const void* __restrict__ src, int n,
                                                 const unsigned* __restrict__ flagw,
                                                 unsigned short* __restrict__ dst){
  int fp32 = (int)*flagw;
  int i0 = blockIdx.x * 256 + threadIdx.x;
  int stride = gridDim.x * 256;
  if (fp32){
    const float* s = (const float*)src;
    for (int i = i0; i < n; i += stride) dst[i] = f2bf(s[i]);
  } else {
    const unsigned short* s = (const unsigned short*)src;
    for (int i = i0; i < n; i += stride) dst[i] = s[i];
  }
}

// -------- diagnostic scans: OR stage bits into *flag on NaN/Inf or |x|>thresh --------
__global__ __launch_bounds__(256) void k_scan_bf16(const unsigned short* __restrict__ buf,
                                                   long n, unsigned bits, float thresh,
                                                   unsigned* __restrict__ flag){
  long i0 = (long)blockIdx.x * 256 + threadIdx.x;
  long stride = (long)gridDim.x * 256;
  unsigned bad = 0;
  for (long i = i0; i < n; i += stride){
    unsigned short u = buf[i];
    unsigned e = (u >> 7) & 0xFF;
    if (e == 0xFF) bad |= bits;
    float v = bf2f(u);
    if (fabsf(v) > thresh) bad |= bits;
  }
  if (bad) atomicOr(flag, bad);
}
__global__ __launch_bounds__(256) void k_scan_f32(const float* __restrict__ buf,
                                                  long n, unsigned bits, float thresh,
                                                  unsigned* __restrict__ flag){
  long i0 = (long)blockIdx.x * 256 + threadIdx.x;
  long stride = (long)gridDim.x * 256;
  unsigned bad = 0;
  for (long i = i0; i < n; i += stride){
    float v = buf[i];
    if (!(v == v) || fabsf(v) > thresh) bad |= bits;
  }
  if (bad) atomicOr(flag, bad);
}

// ---------------- embed: x[t*B+b][e] = embc[inputs[b][t]][e] (bf16) ----------------
__global__ __launch_bounds__(256) void k_embed(const unsigned short* __restrict__ embc,
                                               const void* __restrict__ inputs,
                                               const unsigned* __restrict__ i64f,
                                               unsigned short* __restrict__ x){
  int c = blockIdx.x * 256 + threadIdx.x;  // 16B chunk id; total = MM*16
  int e8 = (c & 15) * 8;
  int tb = c >> 4;
  int t = tb >> 8;
  int b = tb & 255;
  long k = (long)b * TT + t;
  int idx = (*i64f) ? ((const int*)inputs)[k * 2] : ((const int*)inputs)[k];
  idx = idx < 0 ? 0 : (idx > 64 ? 64 : idx);   // safety clamp (no OOB even if probe wrong)
  *(bf16x8*)(x + (long)tb * EE + e8) = *(const bf16x8*)(embc + (long)idx * EE + e8);
}

// ------- chunk xp GEMM: out[16384][768] = A[16384][K] @ W[768][K]^T + bias (one dir) -------
template<int K>
__global__ __launch_bounds__(256) void k_gemm_chunk(const unsigned short* __restrict__ A,
                                                    const unsigned short* __restrict__ W,
                                                    const unsigned short* __restrict__ bias,
                                                    unsigned short* __restrict__ out){
  __shared__ __align__(16) unsigned short As[128 * 72];
  __shared__ __align__(16) unsigned short Bs[128 * 72];
  int tid = threadIdx.x;
  long m0 = (long)blockIdx.x * 128;
  int  n0 = blockIdx.y * 128;
  int wave = tid >> 6, lane = tid & 63;
  int wm = (wave & 1) * 64, wn = (wave >> 1) * 64;
  int ln16 = lane & 15, quad = lane >> 4;
  f32x4 acc[4][4];
  #pragma unroll
  for (int i = 0; i < 4; i++)
    #pragma unroll
    for (int j = 0; j < 4; j++) acc[i][j] = (f32x4){0.f,0.f,0.f,0.f};

  for (int k0 = 0; k0 < K; k0 += 64){
    #pragma unroll
    for (int i = 0; i < 4; i++){
      int c = tid + 256 * i;        // 1024 chunks of 8 bf16
      int row = c >> 3, koff = (c & 7) * 8;
      *(bf16x8*)&As[row * 72 + koff] = *(const bf16x8*)&A[(m0 + row) * K + k0 + koff];
      *(bf16x8*)&Bs[row * 72 + koff] = *(const bf16x8*)&W[(long)(n0 + row) * K + k0 + koff];
    }
    __syncthreads();
    #pragma unroll
    for (int kk = 0; kk < 64; kk += 32){
      bf16x8 af[4], bfr[4];
      #pragma unroll
      for (int mi = 0; mi < 4; mi++) af[mi]  = *(bf16x8*)&As[(wm + mi*16 + ln16) * 72 + kk + quad*8];
      #pragma unroll
      for (int nj = 0; nj < 4; nj++) bfr[nj] = *(bf16x8*)&Bs[(wn + nj*16 + ln16) * 72 + kk + quad*8];
      #pragma unroll
      for (int mi = 0; mi < 4; mi++)
        #pragma unroll
        for (int nj = 0; nj < 4; nj++)
          acc[mi][nj] = __builtin_amdgcn_mfma_f32_16x16x32_bf16(af[mi], bfr[nj], acc[mi][nj], 0, 0, 0);
    }
    __syncthreads();
  }
  #pragma unroll
  for (int mi = 0; mi < 4; mi++)
    #pragma unroll
    for (int nj = 0; nj < 4; nj++){
      int n = n0 + wn + nj*16 + ln16;
      float bv = bf2f(bias[n]);
      #pragma unroll
      for (int r = 0; r < 4; r++){
        long m = m0 + wm + mi*16 + quad*4 + r;
        out[m * 768 + n] = f2bf(acc[mi][nj][r] + bv);
      }
    }
}

// ---------------- GRU recurrence over one 64-step chunk, both dirs ----------------
__global__ __launch_bounds__(512) void k_gru_chunk(const unsigned short* __restrict__ xpf,
                                                   const unsigned short* __restrict__ xpb,
                                                   const unsigned short* __restrict__ whh,
                                                   const unsigned short* __restrict__ bhh,
                                                   float* __restrict__ hstate,  // [2][256][256]
                                                   unsigned short* __restrict__ outf,
                                                   unsigned short* __restrict__ outb,
                                                   int out_full, int t0f, int t0b){
  __shared__ __align__(16) unsigned short h_bf[16 * 264];
  int tid = threadIdx.x;
  int dir = blockIdx.x >> 4;
  int b0  = (blockIdx.x & 15) * 16;
  int wave = tid >> 6, lane = tid & 63;
  int ln16 = lane & 15, quad = lane >> 4;
  const unsigned short* xp = dir ? xpb : xpf;
  unsigned short* outp = dir ? outb : outf;
  int t0 = dir ? t0b : t0f;

  float h_old[2][4];
  #pragma unroll
  for (int i = 0; i < 2; i++){
    int c = (wave*2 + i)*16 + ln16;
    #pragma unroll
    for (int r = 0; r < 4; r++){
      int b = quad*4 + r;
      float hv = hstate[((long)dir*256 + b0 + b)*256 + c];
      h_old[i][r] = hv;
      h_bf[b * 264 + c] = f2bf(hv);
    }
  }
  float bh_r[2], bh_z[2], bh_n[2];
  #pragma unroll
  for (int i = 0; i < 2; i++){
    int c = (wave*2 + i)*16 + ln16;
    bh_r[i] = bf2f(bhh[dir*768 + c]);
    bh_z[i] = bf2f(bhh[dir*768 + 256 + c]);
    bh_n[i] = bf2f(bhh[dir*768 + 512 + c]);
  }
  __syncthreads();

  for (int ss = 0; ss < CT; ss++){
    int tl = dir ? (CT - 1 - ss) : ss;
    bf16x8 af[8];
    #pragma unroll
    for (int kt = 0; kt < 8; kt++)
      af[kt] = *(bf16x8*)&h_bf[ln16 * 264 + kt*32 + quad*8];
    __syncthreads();

    #pragma unroll
    for (int i = 0; i < 2; i++){
      int c = (wave*2 + i)*16 + ln16;
      const unsigned short* Wr = whh + ((long)(dir*768 + c)) * 256;
      const unsigned short* Wz = Wr + 256 * 256;
      const unsigned short* Wn = Wr + 512 * 256;
      f32x4 accr = (f32x4){0.f,0.f,0.f,0.f};
      f32x4 accz = (f32x4){0.f,0.f,0.f,0.f};
      f32x4 accn = (f32x4){0.f,0.f,0.f,0.f};
      #pragma unroll
      for (int kt = 0; kt < 8; kt++){
        int ko = kt*32 + quad*8;
        bf16x8 br = *(const bf16x8*)(Wr + ko);
        bf16x8 bz = *(const bf16x8*)(Wz + ko);
        bf16x8 bn = *(const bf16x8*)(Wn + ko);
        accr = __builtin_amdgcn_mfma_f32_16x16x32_bf16(af[kt], br, accr, 0, 0, 0);
        accz = __builtin_amdgcn_mfma_f32_16x16x32_bf16(af[kt], bz, accz, 0, 0, 0);
        accn = __builtin_amdgcn_mfma_f32_16x16x32_bf16(af[kt], bn, accn, 0, 0, 0);
      }
      long xbase = ((long)tl * 256 + b0 + quad*4) * 768 + c;
      #pragma unroll
      for (int r = 0; r < 4; r++){
        float xr = bf2f(xp[xbase + (long)r * 768]);
        float xz = bf2f(xp[xbase + (long)r * 768 + 256]);
        float xn = bf2f(xp[xbase + (long)r * 768 + 512]);
        float rg = sigm(xr + accr[r] + bh_r[i]);
        float zg = sigm(xz + accz[r] + bh_z[i]);
        float ng = tanh_f(xn + rg * (accn[r] + bh_n[i]));
        float hnew = (1.f - zg) * ng + zg * h_old[i][r];
        h_old[i][r] = hnew;
        unsigned short hb = f2bf(hnew);
        int b = b0 + quad*4 + r;
        h_bf[(quad*4 + r) * 264 + c] = hb;
        long oidx = out_full ? (((long)(t0 + tl) * 256 + b) * 512 + dir*256 + c)
                             : (((long)tl * 256 + b) * 256 + c);
        outp[oidx] = hb;
      }
    }
    __syncthreads();
  }

  #pragma unroll
  for (int i = 0; i < 2; i++){
    int c = (wave*2 + i)*16 + ln16;
    #pragma unroll
    for (int r = 0; r < 4; r++)
      hstate[((long)dir*256 + b0 + quad*4 + r)*256 + c] = h_old[i][r];
  }
}

// ------- FC1 per-chunk split-K: fc1acc[b][n] += sum_{t in chunk, c} h2c * W1 -------
// W1 accessed raw (fp32 or bf16 per flag).
__global__ __launch_bounds__(256) void k_fc1_chunk(const unsigned short* __restrict__ h2c,
                                                   const void* __restrict__ W1,
                                                   const unsigned* __restrict__ w1f,
                                                   int t0, int dircol,
                                                   float* __restrict__ fc1acc){
  int mb = blockIdx.x & 3, kb = blockIdx.x >> 2;
  int wave = threadIdx.x >> 6, lane = threadIdx.x & 63;
  int ln16 = lane & 15, quad = lane >> 4;
  int w1fp32 = (int)*w1f;
  f32x4 acc[8];
  #pragma unroll
  for (int nt = 0; nt < 8; nt++) acc[nt] = (f32x4){0.f,0.f,0.f,0.f};

  for (int tt = 0; tt < 4; tt++){
    int tl = kb*4 + tt;
    const unsigned short* A = h2c + ((long)tl * 256 + mb*64 + wave*16) * 256;
    long bbase = (long)(t0 + tl) * 512 + dircol;
    #pragma unroll
    for (int kt = 0; kt < 8; kt++){
      bf16x8 af = *(const bf16x8*)(A + (long)ln16*256 + kt*32 + quad*8);
      #pragma unroll
      for (int nt = 0; nt < 8; nt++){
        long off = bbase + (long)(nt*16 + ln16)*262144 + kt*32 + quad*8;
        bf16x8 bfr;
        if (w1fp32){
          const float* p = (const float*)W1 + off;
          #pragma unroll
          for (int j = 0; j < 8; j++) bfr[j] = (short)f2bf(p[j]);
        } else {
          bfr = *(const bf16x8*)((const unsigned short*)W1 + off);
        }
        acc[nt] = __builtin_amdgcn_mfma_f32_16x16x32_bf16(af, bfr, acc[nt], 0, 0, 0);
      }
    }
  }
  #pragma unroll
  for (int nt = 0; nt < 8; nt++)
    #pragma unroll
    for (int r = 0; r < 4; r++){
      int m = mb*64 + wave*16 + quad*4 + r;
      int n = nt*16 + ln16;
      atomicAdd(&fc1acc[m*128 + n], acc[nt][r]);
    }
}

// ------- final: leaky_relu(fc1acc + b1) @ W2 + b2 -> sigmoid (flag-aware, dual dtype out) ----
__global__ __launch_bounds__(256) void k_fc2(const float* __restrict__ fc1acc,
                                             const unsigned short* __restrict__ b1,
                                             const unsigned short* __restrict__ W2,
                                             const unsigned short* __restrict__ b2,
                                             const unsigned* __restrict__ flags,
                                             void* __restrict__ out){
  int b = threadIdx.x;
  float s = bf2f(b2[0]);
  for (int j = 0; j < 128; j++){
    float v = fc1acc[b*128 + j] + bf2f(b1[j]);
    v = v > 0.f ? v : 0.01f * v;
    s += v * bf2f(W2[j]);
  }
  float r = sigm(s);
  unsigned diag = flags[0];
  unsigned embf = flags[1], i64f = flags[14];
  if (diag || !(s == s)){
    unsigned code = (diag & 0x3F) | (embf ? 64u : 0u) | (i64f ? 128u : 0u);
    r = 4.0f * (2.0f + (float)code);
  }
  if (embf) ((float*)out)[b] = r;            // fp32 world -> fp32 output
  else      ((unsigned short*)out)[b] = f2bf(r);
}

extern "C" void kernel_launch(void* const* d_in, const int* in_sizes, int n_in,
                              void* d_out, int out_size, void* d_ws, size_t ws_size,
                              hipStream_t stream) {
  const void* inp  = d_in[0];
  const void* emb  = d_in[1];
  const void* wih0 = d_in[2];
  const void* whh0 = d_in[3];
  const void* bih0 = d_in[4];
  const void* bhh0 = d_in[5];
  const void* wih1 = d_in[6];
  const void* whh1 = d_in[7];
  const void* bih1 = d_in[8];
  const void* bhh1 = d_in[9];
  const void* W1   = d_in[10];
  const void* b1   = d_in[11];
  const void* W2   = d_in[12];
  const void* b2   = d_in[13];
  unsigned short* out = (unsigned short*)d_out;

  // host-side input-order check (element counts are dtype-independent)
  const int expect[14] = {131072, 8320, 196608, 393216, 1536, 1536,
                          786432, 393216, 1536, 1536, 33554432, 128, 128, 1};
  for (int i = 0; i < 14 && i < n_in; i++){
    if (in_sizes[i] != expect[i]){
      k_sentinel<<<1, 256, 0, stream>>>(out, 4.0f * (600.0f + i));
      return;
    }
  }

  // workspace layout (bytes)
  const size_t OFF_X    = 0;                       // x   [131072*128] bf16
  const size_t OFF_H1   = 33554432ul;              // h1  [131072*512] bf16
  const size_t OFF_XPF  = 167772160ul;             // xpf [16384*768] bf16
  const size_t OFF_XPB  = 192937984ul;
  const size_t OFF_H2F  = 218103808ul;             // h2f [16384*256] bf16
  const size_t OFF_H2B  = 226492416ul;
  const size_t OFF_ST   = 234881024ul;             // hstate [2*256*256] f32
  const size_t OFF_FC   = 235405312ul;             // fc1acc [256*128] f32
  const size_t OFF_FLAG = 235536384ul;             // 16 flag words
  const size_t OFF_P    = 235536448ul;             // converted bf16 params (~3.6 MB)
  // param sub-offsets (elements, bf16)
  unsigned short* P;
  const size_t PO_EMB  = 0;        // 8320
  const size_t PO_WIH0 = 8320;     // 196608
  const size_t PO_WHH0 = 204928;   // 393216
  const size_t PO_BIH0 = 598144;   // 1536
  const size_t PO_BHH0 = 599680;   // 1536
  const size_t PO_WIH1 = 601216;   // 786432
  const size_t PO_WHH1 = 1387648;  // 393216
  const size_t PO_BIH1 = 1780864;  // 1536
  const size_t PO_BHH1 = 1782400;  // 1536
  const size_t PO_B1   = 1783936;  // 128
  const size_t PO_W2   = 1784064;  // 128
  const size_t PO_B2   = 1784192;  // 1 (+pad)
  const size_t NEED    = OFF_P + 2*1784200ul;

  if (ws_size < NEED) {
    k_sentinel<<<1, 256, 0, stream>>>(out, (float)(ws_size >> 20));
    return;
  }

  char* ws = (char*)d_ws;
  unsigned short* x    = (unsigned short*)(ws + OFF_X);
  unsigned short* h1   = (unsigned short*)(ws + OFF_H1);
  unsigned short* xpf  = (unsigned short*)(ws + OFF_XPF);
  unsigned short* xpb  = (unsigned short*)(ws + OFF_XPB);
  unsigned short* h2f  = (unsigned short*)(ws + OFF_H2F);
  unsigned short* h2b  = (unsigned short*)(ws + OFF_H2B);
  float*          hst  = (float*)(ws + OFF_ST);
  float*          fc1a = (float*)(ws + OFF_FC);
  unsigned*       flg  = (unsigned*)(ws + OFF_FLAG);
  P = (unsigned short*)(ws + OFF_P);

  hipMemsetAsync(flg, 0, 64, stream);

  // ---- probes: flag words [1..13] = per-tensor fp32 verdicts, [14] = int64 verdict ----
  k_probe_f<<<1,256,0,stream>>>((const unsigned short*)emb,  8320,     flg+1);
  k_probe_f<<<1,256,0,stream>>>((const unsigned short*)wih0, 196608,   flg+2);
  k_probe_f<<<1,256,0,stream>>>((const unsigned short*)whh0, 393216,   flg+3);
  k_probe_f<<<1,256,0,stream>>>((const unsigned short*)bih0, 1536,     flg+4);
  k_probe_f<<<1,256,0,stream>>>((const unsigned short*)bhh0, 1536,     flg+5);
  k_probe_f<<<1,256,0,stream>>>((const unsigned short*)wih1, 786432,   flg+6);
  k_probe_f<<<1,256,0,stream>>>((const unsigned short*)whh1, 393216,   flg+7);
  k_probe_f<<<1,256,0,stream>>>((const unsigned short*)bih1, 1536,     flg+8);
  k_probe_f<<<1,256,0,stream>>>((const unsigned short*)bhh1, 1536,     flg+9);
  k_probe_f<<<1,256,0,stream>>>((const unsigned short*)b1,   128,      flg+10);
  k_probe_f<<<1,256,0,stream>>>((const unsigned short*)W2,   128,      flg+11);
  k_probe_f<<<1,256,0,stream>>>((const unsigned short*)b2,   1,        flg+12);
  k_probe_f<<<1,256,0,stream>>>((const unsigned short*)W1,   33554432, flg+13);
  k_probe_i<<<1,256,0,stream>>>((const int*)inp, 131072, flg+14);

  // ---- convert params to bf16 in ws ----
  k_convert<<<64,256,0,stream>>>(emb,  8320,   flg+1,  P+PO_EMB);
  k_convert<<<64,256,0,stream>>>(wih0, 196608, flg+2,  P+PO_WIH0);
  k_convert<<<64,256,0,stream>>>(whh0, 393216, flg+3,  P+PO_WHH0);
  k_convert<<<8, 256,0,stream>>>(bih0, 1536,   flg+4,  P+PO_BIH0);
  k_convert<<<8, 256,0,stream>>>(bhh0, 1536,   flg+5,  P+PO_BHH0);
  k_convert<<<64,256,0,stream>>>(wih1, 786432, flg+6,  P+PO_WIH1);
  k_convert<<<64,256,0,stream>>>(whh1, 393216, flg+7,  P+PO_WHH1);
  k_convert<<<8, 256,0,stream>>>(bih1, 1536,   flg+8,  P+PO_BIH1);
  k_convert<<<8, 256,0,stream>>>(bhh1, 1536,   flg+9,  P+PO_BHH1);
  k_convert<<<1, 256,0,stream>>>(b1,   128,    flg+10, P+PO_B1);
  k_convert<<<1, 256,0,stream>>>(W2,   128,    flg+11, P+PO_W2);
  k_convert<<<1, 256,0,stream>>>(b2,   1,      flg+12, P+PO_B2);

  k_embed<<<MM*16/256, 256, 0, stream>>>(P+PO_EMB, inp, flg+14, x);
  k_scan_bf16<<<1024, 256, 0, stream>>>(x, (long)MM*EE, 0x1u, 1.0e30f, flg);

  // ---- layer 0 ----
  hipMemsetAsync(hst, 0, 2*256*256*sizeof(float), stream);
  for (int c = 0; c < NCH; c++){
    int t0f = c * CT, t0b = (NCH - 1 - c) * CT;
    k_gemm_chunk<128><<<dim3(CROWS/128, 6), 256, 0, stream>>>(x + (long)t0f*256*128, P+PO_WIH0,          P+PO_BIH0,     xpf);
    k_gemm_chunk<128><<<dim3(CROWS/128, 6), 256, 0, stream>>>(x + (long)t0b*256*128, P+PO_WIH0+768*128,  P+PO_BIH0+768, xpb);
    k_scan_bf16<<<1024, 256, 0, stream>>>(xpf, (long)CROWS*768, 0x2u, 100.f, flg);
    k_scan_bf16<<<1024, 256, 0, stream>>>(xpb, (long)CROWS*768, 0x2u, 100.f, flg);
    k_gru_chunk<<<32, 512, 0, stream>>>(xpf, xpb, P+PO_WHH0, P+PO_BHH0, hst, h1, h1, 1, t0f, t0b);
  }
  k_scan_bf16<<<2048, 256, 0, stream>>>(h1, (long)MM*512, 0x4u, 1.01f, flg);

  // ---- layer 1 (+ fused FC1 accumulation) ----
  hipMemsetAsync(hst, 0, 2*256*256*sizeof(float), stream);
  hipMemsetAsync(fc1a, 0, 256*128*sizeof(float), stream);
  for (int c = 0; c < NCH; c++){
    int t0f = c * CT, t0b = (NCH - 1 - c) * CT;
    k_gemm_chunk<512><<<dim3(CROWS/128, 6), 256, 0, stream>>>(h1 + (long)t0f*256*512, P+PO_WIH1,          P+PO_BIH1,     xpf);
    k_gemm_chunk<512><<<dim3(CROWS/128, 6), 256, 0, stream>>>(h1 + (long)t0b*256*512, P+PO_WIH1+768*512,  P+PO_BIH1+768, xpb);
    k_scan_bf16<<<1024, 256, 0, stream>>>(xpf, (long)CROWS*768, 0x8u, 100.f, flg);
    k_scan_bf16<<<1024, 256, 0, stream>>>(xpb, (long)CROWS*768, 0x8u, 100.f, flg);
    k_gru_chunk<<<32, 512, 0, stream>>>(xpf, xpb, P+PO_WHH1, P+PO_BHH1, hst, h2f, h2b, 0, t0f, t0b);
    k_scan_bf16<<<1024, 256, 0, stream>>>(h2f, (long)CROWS*256, 0x10u, 1.01f, flg);
    k_scan_bf16<<<1024, 256, 0, stream>>>(h2b, (long)CROWS*256, 0x10u, 1.01f, flg);
    k_fc1_chunk<<<64, 256, 0, stream>>>(h2f, W1, flg+13, t0f, 0,   fc1a);
    k_fc1_chunk<<<64, 256, 0, stream>>>(h2b, W1, flg+13, t0b, 256, fc1a);
  }
  k_scan_f32<<<128, 256, 0, stream>>>(fc1a, 256*128, 0x20u, 1.0e3f, flg);

  k_fc2<<<1, 256, 0, stream>>>(fc1a, P+PO_B1, P+PO_W2, P+PO_B2, flg, d_out);
}

// Round 5
// 7770.176 us; speedup vs baseline: 1.1862x; 1.1862x over previous
//
#include <hip/hip_runtime.h>
#include <hip/hip_bf16.h>
#include <stdint.h>

// Problem dims
#define BB 256
#define TT 512
#define EE 128
#define HH 256
#define MM (TT*BB)       // 131072 rows total
#define CT 64            // timesteps per chunk
#define NCH (TT/CT)      // 8 chunks
#define CROWS (CT*BB)    // 16384 rows per chunk

typedef __attribute__((ext_vector_type(8))) short bf16x8;
typedef __attribute__((ext_vector_type(4))) float f32x4;

__device__ __forceinline__ float bf2f(unsigned short u){
  union { unsigned int i; float f; } v; v.i = ((unsigned int)u) << 16; return v.f;
}
__device__ __forceinline__ unsigned short f2bf(float f){
  union { float f; unsigned int i; } v; v.f = f;
  unsigned int u = v.i;
  unsigned int r = (u + 0x7FFFu + ((u >> 16) & 1u)) >> 16;
  return (unsigned short)r;
}
__device__ __forceinline__ float sigm(float x){ return 1.f / (1.f + __expf(-x)); }
__device__ __forceinline__ float tanh_f(float x){
  float e2 = __expf(2.f * x);
  return 1.f - 2.f / (e2 + 1.f);
}

// -------- sentinel --------
__global__ void k_sentinel(unsigned short* out, float v){ out[threadIdx.x] = f2bf(v); }

// -------- dtype probe: is this float tensor fp32 (vs bf16)? --------
__global__ void k_probe_f(const unsigned short* __restrict__ buf, int n,
                          unsigned* __restrict__ flagw){
  __shared__ int cnt;
  if (threadIdx.x == 0) cnt = 0;
  __syncthreads();
  int scanw = n < 4096 ? n : 4096;
  int bad = 0;
  for (int i = threadIdx.x; i < scanw; i += 256){
    unsigned short u = buf[i];
    unsigned e = (u >> 7) & 0xFF;
    if (u != 0 && (e < 0x60 || e == 0xFF)) bad++;
  }
  atomicAdd(&cnt, bad);
  __syncthreads();
  if (threadIdx.x == 0) *flagw = (cnt * 8 > scanw) ? 1u : 0u;
}

// -------- int width probe: int64 iff odd int32 words are (almost) all zero --------
__global__ void k_probe_i(const int* __restrict__ buf, int n, unsigned* __restrict__ flagw){
  __shared__ int cnt;
  if (threadIdx.x == 0) cnt = 0;
  __syncthreads();
  int scan = n < 1024 ? n : 1024;
  int nz = 0;
  for (int i = threadIdx.x; i < scan; i += 256)
    if ((i & 1) && buf[i] != 0) nz++;
  atomicAdd(&cnt, nz);
  __syncthreads();
  if (threadIdx.x == 0) *flagw = (cnt < 10) ? 1u : 0u;
}

// -------- convert a float tensor (fp32 or bf16 per flag) to bf16 dst --------
__global__ __launch_bounds__(256) void k_convert(const void* __restrict__ src, int n,
                                                 const unsigned* __restrict__ flagw,
                                                 unsigned short* __restrict__ dst){
  int fp32 = (int)*flagw;
  int i0 = blockIdx.x * 256 + threadIdx.x;
  int stride = gridDim.x * 256;
  if (fp32){
    const float* s = (const float*)src;
    for (int i = i0; i < n; i += stride) dst[i] = f2bf(s[i]);
  } else {
    const unsigned short* s = (const unsigned short*)src;
    for (int i = i0; i < n; i += stride) dst[i] = s[i];
  }
}

// ---------------- embed: x[t*B+b][e] = embc[inputs[b][t]][e] (bf16) ----------------
__global__ __launch_bounds__(256) void k_embed(const unsigned short* __restrict__ embc,
                                               const void* __restrict__ inputs,
                                               const unsigned* __restrict__ i64f,
                                               unsigned short* __restrict__ x){
  int c = blockIdx.x * 256 + threadIdx.x;  // 16B chunk id; total = MM*16
  int e8 = (c & 15) * 8;
  int tb = c >> 4;
  int t = tb >> 8;
  int b = tb & 255;
  long k = (long)b * TT + t;
  int idx = (*i64f) ? ((const int*)inputs)[k * 2] : ((const int*)inputs)[k];
  idx = idx < 0 ? 0 : (idx > 64 ? 64 : idx);
  *(bf16x8*)(x + (long)tb * EE + e8) = *(const bf16x8*)(embc + (long)idx * EE + e8);
}

// ------- chunk xp GEMM, both dirs (grid.z): out[dir][16384][768] = A_dir @ W_dir^T + b -------
template<int K>
__global__ __launch_bounds__(256) void k_gemm_chunk(const unsigned short* __restrict__ A,
                                                    const unsigned short* __restrict__ W,
                                                    const unsigned short* __restrict__ bias,
                                                    unsigned short* __restrict__ out,
                                                    int t0f, int t0b){
  __shared__ __align__(16) unsigned short As[128 * 72];
  __shared__ __align__(16) unsigned short Bs[128 * 72];
  int dir = blockIdx.z;
  const unsigned short* Ad = A + (long)(dir ? t0b : t0f) * 256 * K;
  const unsigned short* Wd = W + (long)dir * 768 * K;
  const unsigned short* bd = bias + dir * 768;
  unsigned short* od = out + (long)dir * CROWS * 768;

  int tid = threadIdx.x;
  long m0 = (long)blockIdx.x * 128;
  int  n0 = blockIdx.y * 128;
  int wave = tid >> 6, lane = tid & 63;
  int wm = (wave & 1) * 64, wn = (wave >> 1) * 64;
  int ln16 = lane & 15, quad = lane >> 4;
  f32x4 acc[4][4];
  #pragma unroll
  for (int i = 0; i < 4; i++)
    #pragma unroll
    for (int j = 0; j < 4; j++) acc[i][j] = (f32x4){0.f,0.f,0.f,0.f};

  for (int k0 = 0; k0 < K; k0 += 64){
    #pragma unroll
    for (int i = 0; i < 4; i++){
      int c = tid + 256 * i;        // 1024 chunks of 8 bf16
      int row = c >> 3, koff = (c & 7) * 8;
      *(bf16x8*)&As[row * 72 + koff] = *(const bf16x8*)&Ad[(m0 + row) * K + k0 + koff];
      *(bf16x8*)&Bs[row * 72 + koff] = *(const bf16x8*)&Wd[(long)(n0 + row) * K + k0 + koff];
    }
    __syncthreads();
    #pragma unroll
    for (int kk = 0; kk < 64; kk += 32){
      bf16x8 af[4], bfr[4];
      #pragma unroll
      for (int mi = 0; mi < 4; mi++) af[mi]  = *(bf16x8*)&As[(wm + mi*16 + ln16) * 72 + kk + quad*8];
      #pragma unroll
      for (int nj = 0; nj < 4; nj++) bfr[nj] = *(bf16x8*)&Bs[(wn + nj*16 + ln16) * 72 + kk + quad*8];
      #pragma unroll
      for (int mi = 0; mi < 4; mi++)
        #pragma unroll
        for (int nj = 0; nj < 4; nj++)
          acc[mi][nj] = __builtin_amdgcn_mfma_f32_16x16x32_bf16(af[mi], bfr[nj], acc[mi][nj], 0, 0, 0);
    }
    __syncthreads();
  }
  #pragma unroll
  for (int mi = 0; mi < 4; mi++)
    #pragma unroll
    for (int nj = 0; nj < 4; nj++){
      int n = n0 + wn + nj*16 + ln16;
      float bv = bf2f(bd[n]);
      #pragma unroll
      for (int r = 0; r < 4; r++){
        long m = m0 + wm + mi*16 + quad*4 + r;
        od[m * 768 + n] = f2bf(acc[mi][nj][r] + bv);
      }
    }
}

// ---------------- GRU recurrence over one 64-step chunk, both dirs ----------------
// grid = 32 blocks (dir = blk>>4, batch group of 16 = blk&15), 512 threads (8 waves).
// r,z weight fragments resident in VGPRs (128 regs); n-gate streamed with 1-deep prefetch.
// Double-buffered LDS h -> single barrier per step.
__global__ __launch_bounds__(512) void k_gru_chunk(const unsigned short* __restrict__ xp2,
                                                   const unsigned short* __restrict__ whh,
                                                   const unsigned short* __restrict__ bhh,
                                                   float* __restrict__ hstate,  // [2][256][256]
                                                   unsigned short* __restrict__ outf,
                                                   unsigned short* __restrict__ outb,
                                                   int out_full, int t0f, int t0b){
  __shared__ __align__(16) unsigned short h_bf[2][16 * 264];
  int tid = threadIdx.x;
  int dir = blockIdx.x >> 4;
  int b0  = (blockIdx.x & 15) * 16;
  int wave = tid >> 6, lane = tid & 63;
  int ln16 = lane & 15, quad = lane >> 4;
  const unsigned short* xp = xp2 + (long)dir * CROWS * 768;
  unsigned short* outp = dir ? outb : outf;
  int t0 = dir ? t0b : t0f;

  // preload r,z weight fragments (once per chunk): 32 x bf16x8 = 128 VGPR
  bf16x8 wr[2][8], wz[2][8];
  const unsigned short* WnP[2];
  #pragma unroll
  for (int i = 0; i < 2; i++){
    int c = (wave*2 + i)*16 + ln16;
    const unsigned short* Wb = whh + ((long)(dir*768 + c)) * 256 + quad*8;
    #pragma unroll
    for (int kt = 0; kt < 8; kt++){
      wr[i][kt] = *(const bf16x8*)(Wb + kt*32);
      wz[i][kt] = *(const bf16x8*)(Wb + 256*256 + kt*32);
    }
    WnP[i] = Wb + 512*256;
  }

  // carried state -> regs + LDS buffer 0
  float h_old[2][4];
  #pragma unroll
  for (int i = 0; i < 2; i++){
    int c = (wave*2 + i)*16 + ln16;
    #pragma unroll
    for (int r = 0; r < 4; r++){
      int b = quad*4 + r;
      float hv = hstate[((long)dir*256 + b0 + b)*256 + c];
      h_old[i][r] = hv;
      h_bf[0][b * 264 + c] = f2bf(hv);
    }
  }
  float bh_r[2], bh_z[2], bh_n[2];
  #pragma unroll
  for (int i = 0; i < 2; i++){
    int c = (wave*2 + i)*16 + ln16;
    bh_r[i] = bf2f(bhh[dir*768 + c]);
    bh_z[i] = bf2f(bhh[dir*768 + 256 + c]);
    bh_n[i] = bf2f(bhh[dir*768 + 512 + c]);
  }
  __syncthreads();

  int p = 0;
  for (int ss = 0; ss < CT; ss++){
    int tl = dir ? (CT - 1 - ss) : ss;
    bf16x8 af[8];
    #pragma unroll
    for (int kt = 0; kt < 8; kt++)
      af[kt] = *(bf16x8*)&h_bf[p][ln16 * 264 + kt*32 + quad*8];

    f32x4 ar[2], az[2], an[2];
    #pragma unroll
    for (int i = 0; i < 2; i++){
      ar[i] = (f32x4){0.f,0.f,0.f,0.f};
      az[i] = (f32x4){0.f,0.f,0.f,0.f};
      an[i] = (f32x4){0.f,0.f,0.f,0.f};
    }
    bf16x8 bn0 = *(const bf16x8*)(WnP[0]);
    bf16x8 bn1 = *(const bf16x8*)(WnP[1]);
    #pragma unroll
    for (int kt = 0; kt < 8; kt++){
      bf16x8 c0 = bn0, c1 = bn1;
      if (kt < 7){
        bn0 = *(const bf16x8*)(WnP[0] + (kt+1)*32);
        bn1 = *(const bf16x8*)(WnP[1] + (kt+1)*32);
      }
      ar[0] = __builtin_amdgcn_mfma_f32_16x16x32_bf16(af[kt], wr[0][kt], ar[0], 0, 0, 0);
      az[0] = __builtin_amdgcn_mfma_f32_16x16x32_bf16(af[kt], wz[0][kt], az[0], 0, 0, 0);
      an[0] = __builtin_amdgcn_mfma_f32_16x16x32_bf16(af[kt], c0,        an[0], 0, 0, 0);
      ar[1] = __builtin_amdgcn_mfma_f32_16x16x32_bf16(af[kt], wr[1][kt], ar[1], 0, 0, 0);
      az[1] = __builtin_amdgcn_mfma_f32_16x16x32_bf16(af[kt], wz[1][kt], az[1], 0, 0, 0);
      an[1] = __builtin_amdgcn_mfma_f32_16x16x32_bf16(af[kt], c1,        an[1], 0, 0, 0);
    }

    long xbase = ((long)tl * 256 + b0 + quad*4) * 768;
    #pragma unroll
    for (int i = 0; i < 2; i++){
      int c = (wave*2 + i)*16 + ln16;
      #pragma unroll
      for (int r = 0; r < 4; r++){
        float xr = bf2f(xp[xbase + (long)r * 768 + c]);
        float xz = bf2f(xp[xbase + (long)r * 768 + c + 256]);
        float xn = bf2f(xp[xbase + (long)r * 768 + c + 512]);
        float rg = sigm(xr + ar[i][r] + bh_r[i]);
        float zg = sigm(xz + az[i][r] + bh_z[i]);
        float ng = tanh_f(xn + rg * (an[i][r] + bh_n[i]));
        float hnew = (1.f - zg) * ng + zg * h_old[i][r];
        h_old[i][r] = hnew;
        unsigned short hb = f2bf(hnew);
        int b = b0 + quad*4 + r;
        h_bf[1-p][(quad*4 + r) * 264 + c] = hb;
        long oidx = out_full ? (((long)(t0 + tl) * 256 + b) * 512 + dir*256 + c)
                             : (((long)tl * 256 + b) * 256 + c);
        outp[oidx] = hb;
      }
    }
    __syncthreads();   // new h_bf[1-p] visible; old buffer free for next overwrite
    p ^= 1;
  }

  #pragma unroll
  for (int i = 0; i < 2; i++){
    int c = (wave*2 + i)*16 + ln16;
    #pragma unroll
    for (int r = 0; r < 4; r++)
      hstate[((long)dir*256 + b0 + quad*4 + r)*256 + c] = h_old[i][r];
  }
}

// ------- FC1 per-chunk split-K, both dirs (grid.y): fc1acc += h2[dir] @ W1_dir-slice -------
__global__ __launch_bounds__(256) void k_fc1_chunk(const unsigned short* __restrict__ h2,
                                                   const void* __restrict__ W1,
                                                   const unsigned* __restrict__ w1f,
                                                   int t0f, int t0b,
                                                   float* __restrict__ fc1acc){
  int dir = blockIdx.y;
  const unsigned short* h2d = h2 + (long)dir * CROWS * 256;
  int t0 = dir ? t0b : t0f;
  int dircol = dir * 256;
  int mb = blockIdx.x & 3, kb = blockIdx.x >> 2;
  int wave = threadIdx.x >> 6, lane = threadIdx.x & 63;
  int ln16 = lane & 15, quad = lane >> 4;
  int w1fp32 = (int)*w1f;
  f32x4 acc[8];
  #pragma unroll
  for (int nt = 0; nt < 8; nt++) acc[nt] = (f32x4){0.f,0.f,0.f,0.f};

  for (int tt = 0; tt < 4; tt++){
    int tl = kb*4 + tt;
    const unsigned short* A = h2d + ((long)tl * 256 + mb*64 + wave*16) * 256;
    long bbase = (long)(t0 + tl) * 512 + dircol;
    #pragma unroll
    for (int kt = 0; kt < 8; kt++){
      bf16x8 af = *(const bf16x8*)(A + (long)ln16*256 + kt*32 + quad*8);
      #pragma unroll
      for (int nt = 0; nt < 8; nt++){
        long off = bbase + (long)(nt*16 + ln16)*262144 + kt*32 + quad*8;
        bf16x8 bfr;
        if (w1fp32){
          const float* pp = (const float*)W1 + off;
          #pragma unroll
          for (int j = 0; j < 8; j++) bfr[j] = (short)f2bf(pp[j]);
        } else {
          bfr = *(const bf16x8*)((const unsigned short*)W1 + off);
        }
        acc[nt] = __builtin_amdgcn_mfma_f32_16x16x32_bf16(af, bfr, acc[nt], 0, 0, 0);
      }
    }
  }
  #pragma unroll
  for (int nt = 0; nt < 8; nt++)
    #pragma unroll
    for (int r = 0; r < 4; r++){
      int m = mb*64 + wave*16 + quad*4 + r;
      int n = nt*16 + ln16;
      atomicAdd(&fc1acc[m*128 + n], acc[nt][r]);
    }
}

// ------- final: leaky_relu(fc1acc + b1) @ W2 + b2 -> sigmoid -------
__global__ __launch_bounds__(256) void k_fc2(const float* __restrict__ fc1acc,
                                             const unsigned short* __restrict__ b1,
                                             const unsigned short* __restrict__ W2,
                                             const unsigned short* __restrict__ b2,
                                             const unsigned* __restrict__ flags,
                                             void* __restrict__ out){
  int b = threadIdx.x;
  float s = bf2f(b2[0]);
  for (int j = 0; j < 128; j++){
    float v = fc1acc[b*128 + j] + bf2f(b1[j]);
    v = v > 0.f ? v : 0.01f * v;
    s += v * bf2f(W2[j]);
  }
  float r = sigm(s);
  if (flags[1]) ((float*)out)[b] = r;          // fp32 world -> fp32 output
  else          ((unsigned short*)out)[b] = f2bf(r);
}

extern "C" void kernel_launch(void* const* d_in, const int* in_sizes, int n_in,
                              void* d_out, int out_size, void* d_ws, size_t ws_size,
                              hipStream_t stream) {
  const void* inp  = d_in[0];
  const void* emb  = d_in[1];
  const void* wih0 = d_in[2];
  const void* whh0 = d_in[3];
  const void* bih0 = d_in[4];
  const void* bhh0 = d_in[5];
  const void* wih1 = d_in[6];
  const void* whh1 = d_in[7];
  const void* bih1 = d_in[8];
  const void* bhh1 = d_in[9];
  const void* W1   = d_in[10];
  const void* b1   = d_in[11];
  const void* W2   = d_in[12];
  const void* b2   = d_in[13];
  unsigned short* out = (unsigned short*)d_out;

  const int expect[14] = {131072, 8320, 196608, 393216, 1536, 1536,
                          786432, 393216, 1536, 1536, 33554432, 128, 128, 1};
  for (int i = 0; i < 14 && i < n_in; i++){
    if (in_sizes[i] != expect[i]){
      k_sentinel<<<1, 256, 0, stream>>>(out, 4.0f * (600.0f + i));
      return;
    }
  }

  // workspace layout (bytes)
  const size_t OFF_X    = 0;                       // x   [131072*128] bf16
  const size_t OFF_H1   = 33554432ul;              // h1  [131072*512] bf16
  const size_t OFF_XP   = 167772160ul;             // xp  [2][16384*768] bf16 (50.3 MB)
  const size_t OFF_H2   = 218103808ul;             // h2  [2][16384*256] bf16 (16.8 MB)
  const size_t OFF_ST   = 234881024ul;             // hstate [2*256*256] f32
  const size_t OFF_FC   = 235405312ul;             // fc1acc [256*128] f32
  const size_t OFF_FLAG = 235536384ul;             // 16 flag words
  const size_t OFF_P    = 235536448ul;             // converted bf16 params (~3.6 MB)
  unsigned short* P;
  const size_t PO_EMB  = 0;        // 8320
  const size_t PO_WIH0 = 8320;     // 196608
  const size_t PO_WHH0 = 204928;   // 393216
  const size_t PO_BIH0 = 598144;   // 1536
  const size_t PO_BHH0 = 599680;   // 1536
  const size_t PO_WIH1 = 601216;   // 786432
  const size_t PO_WHH1 = 1387648;  // 393216
  const size_t PO_BIH1 = 1780864;  // 1536
  const size_t PO_BHH1 = 1782400;  // 1536
  const size_t PO_B1   = 1783936;  // 128
  const size_t PO_W2   = 1784064;  // 128
  const size_t PO_B2   = 1784192;  // 1 (+pad)
  const size_t NEED    = OFF_P + 2*1784200ul;

  if (ws_size < NEED) {
    k_sentinel<<<1, 256, 0, stream>>>(out, (float)(ws_size >> 20));
    return;
  }

  char* ws = (char*)d_ws;
  unsigned short* x    = (unsigned short*)(ws + OFF_X);
  unsigned short* h1   = (unsigned short*)(ws + OFF_H1);
  unsigned short* xp   = (unsigned short*)(ws + OFF_XP);
  unsigned short* h2   = (unsigned short*)(ws + OFF_H2);
  unsigned short* h2b  = h2 + (long)CROWS*256;
  float*          hst  = (float*)(ws + OFF_ST);
  float*          fc1a = (float*)(ws + OFF_FC);
  unsigned*       flg  = (unsigned*)(ws + OFF_FLAG);
  P = (unsigned short*)(ws + OFF_P);

  hipMemsetAsync(flg, 0, 64, stream);

  // ---- dtype probes ----
  k_probe_f<<<1,256,0,stream>>>((const unsigned short*)emb,  8320,     flg+1);
  k_probe_f<<<1,256,0,stream>>>((const unsigned short*)wih0, 196608,   flg+2);
  k_probe_f<<<1,256,0,stream>>>((const unsigned short*)whh0, 393216,   flg+3);
  k_probe_f<<<1,256,0,stream>>>((const unsigned short*)bih0, 1536,     flg+4);
  k_probe_f<<<1,256,0,stream>>>((const unsigned short*)bhh0, 1536,     flg+5);
  k_probe_f<<<1,256,0,stream>>>((const unsigned short*)wih1, 786432,   flg+6);
  k_probe_f<<<1,256,0,stream>>>((const unsigned short*)whh1, 393216,   flg+7);
  k_probe_f<<<1,256,0,stream>>>((const unsigned short*)bih1, 1536,     flg+8);
  k_probe_f<<<1,256,0,stream>>>((const unsigned short*)bhh1, 1536,     flg+9);
  k_probe_f<<<1,256,0,stream>>>((const unsigned short*)b1,   128,      flg+10);
  k_probe_f<<<1,256,0,stream>>>((const unsigned short*)W2,   128,      flg+11);
  k_probe_f<<<1,256,0,stream>>>((const unsigned short*)b2,   1,        flg+12);
  k_probe_f<<<1,256,0,stream>>>((const unsigned short*)W1,   33554432, flg+13);
  k_probe_i<<<1,256,0,stream>>>((const int*)inp, 131072, flg+14);

  // ---- convert params to bf16 ----
  k_convert<<<64,256,0,stream>>>(emb,  8320,   flg+1,  P+PO_EMB);
  k_convert<<<64,256,0,stream>>>(wih0, 196608, flg+2,  P+PO_WIH0);
  k_convert<<<64,256,0,stream>>>(whh0, 393216, flg+3,  P+PO_WHH0);
  k_convert<<<8, 256,0,stream>>>(bih0, 1536,   flg+4,  P+PO_BIH0);
  k_convert<<<8, 256,0,stream>>>(bhh0, 1536,   flg+5,  P+PO_BHH0);
  k_convert<<<64,256,0,stream>>>(wih1, 786432, flg+6,  P+PO_WIH1);
  k_convert<<<64,256,0,stream>>>(whh1, 393216, flg+7,  P+PO_WHH1);
  k_convert<<<8, 256,0,stream>>>(bih1, 1536,   flg+8,  P+PO_BIH1);
  k_convert<<<8, 256,0,stream>>>(bhh1, 1536,   flg+9,  P+PO_BHH1);
  k_convert<<<1, 256,0,stream>>>(b1,   128,    flg+10, P+PO_B1);
  k_convert<<<1, 256,0,stream>>>(W2,   128,    flg+11, P+PO_W2);
  k_convert<<<1, 256,0,stream>>>(b2,   1,      flg+12, P+PO_B2);

  k_embed<<<MM*16/256, 256, 0, stream>>>(P+PO_EMB, inp, flg+14, x);

  // ---- layer 0 ----
  hipMemsetAsync(hst, 0, 2*256*256*sizeof(float), stream);
  for (int c = 0; c < NCH; c++){
    int t0f = c * CT, t0b = (NCH - 1 - c) * CT;
    k_gemm_chunk<128><<<dim3(CROWS/128, 6, 2), 256, 0, stream>>>(x, P+PO_WIH0, P+PO_BIH0, xp, t0f, t0b);
    k_gru_chunk<<<32, 512, 0, stream>>>(xp, P+PO_WHH0, P+PO_BHH0, hst, h1, h1, 1, t0f, t0b);
  }

  // ---- layer 1 (+ fused FC1 accumulation) ----
  hipMemsetAsync(hst, 0, 2*256*256*sizeof(float), stream);
  hipMemsetAsync(fc1a, 0, 256*128*sizeof(float), stream);
  for (int c = 0; c < NCH; c++){
    int t0f = c * CT, t0b = (NCH - 1 - c) * CT;
    k_gemm_chunk<512><<<dim3(CROWS/128, 6, 2), 256, 0, stream>>>(h1, P+PO_WIH1, P+PO_BIH1, xp, t0f, t0b);
    k_gru_chunk<<<32, 512, 0, stream>>>(xp, P+PO_WHH1, P+PO_BHH1, hst, h2, h2b, 0, t0f, t0b);
    k_fc1_chunk<<<dim3(64, 2), 256, 0, stream>>>(h2, W1, flg+13, t0f, t0b, fc1a);
  }

  k_fc2<<<1, 256, 0, stream>>>(fc1a, P+PO_B1, P+PO_W2, P+PO_B2, flg, d_out);
}

// Round 6
// 7066.166 us; speedup vs baseline: 1.3044x; 1.0996x over previous
//
#include <hip/hip_runtime.h>
#include <hip/hip_bf16.h>
#include <stdint.h>

// Problem dims
#define BB 256
#define TT 512
#define EE 128
#define HH 256
#define MM (TT*BB)       // 131072 rows total
#define CT 64            // timesteps per chunk
#define NCH (TT/CT)      // 8 chunks
#define CROWS (CT*BB)    // 16384 rows per chunk
// swizzled xp sizes (shorts)
#define RZ_DIR 8388608   // 64*16*8*64*16
#define RZ_TL  131072    // 16*8*64*16
#define N_DIR  4194304   // 64*16*8*64*8
#define N_TL   65536

typedef __attribute__((ext_vector_type(8))) short bf16x8;
typedef __attribute__((ext_vector_type(4))) float f32x4;

__device__ __forceinline__ float bf2f(unsigned short u){
  union { unsigned int i; float f; } v; v.i = ((unsigned int)u) << 16; return v.f;
}
__device__ __forceinline__ unsigned short f2bf(float f){
  union { float f; unsigned int i; } v; v.f = f;
  unsigned int u = v.i;
  unsigned int r = (u + 0x7FFFu + ((u >> 16) & 1u)) >> 16;
  return (unsigned short)r;
}
__device__ __forceinline__ float sigm(float x){ return 1.f / (1.f + __expf(-x)); }
__device__ __forceinline__ float tanh_f(float x){
  float e2 = __expf(2.f * x);
  return 1.f - 2.f / (e2 + 1.f);
}

// -------- sentinel --------
__global__ void k_sentinel(unsigned short* out, float v){ out[threadIdx.x] = f2bf(v); }

// -------- dtype probe: is this float tensor fp32 (vs bf16)? --------
__global__ void k_probe_f(const unsigned short* __restrict__ buf, int n,
                          unsigned* __restrict__ flagw){
  __shared__ int cnt;
  if (threadIdx.x == 0) cnt = 0;
  __syncthreads();
  int scanw = n < 4096 ? n : 4096;
  int bad = 0;
  for (int i = threadIdx.x; i < scanw; i += 256){
    unsigned short u = buf[i];
    unsigned e = (u >> 7) & 0xFF;
    if (u != 0 && (e < 0x60 || e == 0xFF)) bad++;
  }
  atomicAdd(&cnt, bad);
  __syncthreads();
  if (threadIdx.x == 0) *flagw = (cnt * 8 > scanw) ? 1u : 0u;
}

// -------- int width probe: int64 iff odd int32 words are (almost) all zero --------
__global__ void k_probe_i(const int* __restrict__ buf, int n, unsigned* __restrict__ flagw){
  __shared__ int cnt;
  if (threadIdx.x == 0) cnt = 0;
  __syncthreads();
  int scan = n < 1024 ? n : 1024;
  int nz = 0;
  for (int i = threadIdx.x; i < scan; i += 256)
    if ((i & 1) && buf[i] != 0) nz++;
  atomicAdd(&cnt, nz);
  __syncthreads();
  if (threadIdx.x == 0) *flagw = (cnt < 10) ? 1u : 0u;
}

// -------- convert a float tensor (fp32 or bf16 per flag) to bf16 dst --------
__global__ __launch_bounds__(256) void k_convert(const void* __restrict__ src, int n,
                                                 const unsigned* __restrict__ flagw,
                                                 unsigned short* __restrict__ dst){
  int fp32 = (int)*flagw;
  int i0 = blockIdx.x * 256 + threadIdx.x;
  int stride = gridDim.x * 256;
  if (fp32){
    const float* s = (const float*)src;
    for (int i = i0; i < n; i += stride) dst[i] = f2bf(s[i]);
  } else {
    const unsigned short* s = (const unsigned short*)src;
    for (int i = i0; i < n; i += stride) dst[i] = s[i];
  }
}

// ---------------- embed: x[t*B+b][e] = embc[inputs[b][t]][e] (bf16) ----------------
__global__ __launch_bounds__(256) void k_embed(const unsigned short* __restrict__ embc,
                                               const void* __restrict__ inputs,
                                               const unsigned* __restrict__ i64f,
                                               unsigned short* __restrict__ x){
  int c = blockIdx.x * 256 + threadIdx.x;  // 16B chunk id; total = MM*16
  int e8 = (c & 15) * 8;
  int tb = c >> 4;
  int t = tb >> 8;
  int b = tb & 255;
  long k = (long)b * TT + t;
  int idx = (*i64f) ? ((const int*)inputs)[k * 2] : ((const int*)inputs)[k];
  idx = idx < 0 ? 0 : (idx > 64 ? 64 : idx);
  *(bf16x8*)(x + (long)tb * EE + e8) = *(const bf16x8*)(embc + (long)idx * EE + e8);
}

// ------- chunk xp GEMM, both dirs (grid.z), epilogue writes GRU-swizzled xp -------
// xp_rz record (per tl,bg,w,lane): 16 shorts = [i0: r gate r0..3 | z gate r0..3][i1: same]
// xp_n  record: 8 shorts = [i0: n gate r0..3][i1: r0..3]
template<int K>
__global__ __launch_bounds__(256) void k_gemm_chunk(const unsigned short* __restrict__ A,
                                                    const unsigned short* __restrict__ W,
                                                    const unsigned short* __restrict__ bias,
                                                    unsigned short* __restrict__ xprz,
                                                    unsigned short* __restrict__ xpn,
                                                    int t0f, int t0b){
  __shared__ __align__(16) unsigned short As[128 * 72];
  __shared__ __align__(16) unsigned short Bs[128 * 72];
  int dir = blockIdx.z;
  const unsigned short* Ad = A + (long)(dir ? t0b : t0f) * 256 * K;
  const unsigned short* Wd = W + (long)dir * 768 * K;
  const unsigned short* bd = bias + dir * 768;
  unsigned short* rzd = xprz + (long)dir * RZ_DIR;
  unsigned short* nd  = xpn  + (long)dir * N_DIR;

  int tid = threadIdx.x;
  long m0 = (long)blockIdx.x * 128;
  int  n0 = blockIdx.y * 128;
  int wave = tid >> 6, lane = tid & 63;
  int wm = (wave & 1) * 64, wn = (wave >> 1) * 64;
  int ln16 = lane & 15, quad = lane >> 4;
  f32x4 acc[4][4];
  #pragma unroll
  for (int i = 0; i < 4; i++)
    #pragma unroll
    for (int j = 0; j < 4; j++) acc[i][j] = (f32x4){0.f,0.f,0.f,0.f};

  for (int k0 = 0; k0 < K; k0 += 64){
    #pragma unroll
    for (int i = 0; i < 4; i++){
      int c = tid + 256 * i;        // 1024 chunks of 8 bf16
      int row = c >> 3, koff = (c & 7) * 8;
      *(bf16x8*)&As[row * 72 + koff] = *(const bf16x8*)&Ad[(m0 + row) * K + k0 + koff];
      *(bf16x8*)&Bs[row * 72 + koff] = *(const bf16x8*)&Wd[(long)(n0 + row) * K + k0 + koff];
    }
    __syncthreads();
    #pragma unroll
    for (int kk = 0; kk < 64; kk += 32){
      bf16x8 af[4], bfr[4];
      #pragma unroll
      for (int mi = 0; mi < 4; mi++) af[mi]  = *(bf16x8*)&As[(wm + mi*16 + ln16) * 72 + kk + quad*8];
      #pragma unroll
      for (int nj = 0; nj < 4; nj++) bfr[nj] = *(bf16x8*)&Bs[(wn + nj*16 + ln16) * 72 + kk + quad*8];
      #pragma unroll
      for (int mi = 0; mi < 4; mi++)
        #pragma unroll
        for (int nj = 0; nj < 4; nj++)
          acc[mi][nj] = __builtin_amdgcn_mfma_f32_16x16x32_bf16(af[mi], bfr[nj], acc[mi][nj], 0, 0, 0);
    }
    __syncthreads();
  }
  // swizzled epilogue
  #pragma unroll
  for (int mi = 0; mi < 4; mi++)
    #pragma unroll
    for (int nj = 0; nj < 4; nj++){
      int n = n0 + wn + nj*16 + ln16;       // 0..767 within dir
      int g = n >> 8, c = n & 255;
      int w = c >> 5, ii = (c >> 4) & 1;
      float bv = bf2f(bd[n]);
      #pragma unroll
      for (int r = 0; r < 4; r++){
        long m = m0 + wm + mi*16 + quad*4 + r;
        int tl = (int)(m >> 8);
        int bgx = ((int)m & 255) >> 4;      // m&15 == quad*4+r
        long rec = (((long)tl*16 + bgx)*8 + w)*64 + quad*16 + ln16;
        unsigned short val = f2bf(acc[mi][nj][r] + bv);
        if (g < 2) rzd[rec*16 + ii*8 + g*4 + r] = val;
        else       nd [rec*8  + ii*4 + r]       = val;
      }
    }
}

// ---------------- GRU recurrence over one 64-step chunk, both dirs ----------------
// grid = 32 blocks (dir = blk>>4, batch group of 16 = blk&15), 512 threads (8 waves).
// xp read as 3 coalesced dwordx4/lane/step, register-prefetched one step ahead.
// r-weights resident in VGPRs; z,n streamed from L2 with 2-deep kt prefetch.
__global__ __launch_bounds__(512) void k_gru_chunk(const unsigned short* __restrict__ xprz,
                                                   const unsigned short* __restrict__ xpn,
                                                   const unsigned short* __restrict__ whh,
                                                   const unsigned short* __restrict__ bhh,
                                                   float* __restrict__ hstate,  // [2][256][256]
                                                   unsigned short* __restrict__ outf,
                                                   unsigned short* __restrict__ outb,
                                                   int out_full, int t0f, int t0b){
  __shared__ __align__(16) unsigned short h_bf[2][16 * 264];
  int tid = threadIdx.x;
  int dir = blockIdx.x >> 4;
  int bg  = blockIdx.x & 15;
  int b0  = bg * 16;
  int wave = tid >> 6, lane = tid & 63;
  int ln16 = lane & 15, quad = lane >> 4;
  unsigned short* outp = dir ? outb : outf;
  int t0 = dir ? t0b : t0f;

  const unsigned short* rzbase = xprz + (long)dir * RZ_DIR + ((long)(bg*8 + wave)*64 + lane) * 16;
  const unsigned short* nbase  = xpn  + (long)dir * N_DIR  + ((long)(bg*8 + wave)*64 + lane) * 8;

  // resident r-gate weight fragments (64 VGPR); z,n stream pointers
  bf16x8 wr[2][8];
  const unsigned short* WzP[2];
  const unsigned short* WnP[2];
  #pragma unroll
  for (int i = 0; i < 2; i++){
    int c = (wave*2 + i)*16 + ln16;
    const unsigned short* Wb = whh + ((long)(dir*768 + c)) * 256 + quad*8;
    #pragma unroll
    for (int kt = 0; kt < 8; kt++) wr[i][kt] = *(const bf16x8*)(Wb + kt*32);
    WzP[i] = Wb + 256*256;
    WnP[i] = Wb + 512*256;
  }

  // carried state -> regs + LDS buffer 0
  float h_old[2][4];
  #pragma unroll
  for (int i = 0; i < 2; i++){
    int c = (wave*2 + i)*16 + ln16;
    #pragma unroll
    for (int r = 0; r < 4; r++){
      int b = quad*4 + r;
      float hv = hstate[((long)dir*256 + b0 + b)*256 + c];
      h_old[i][r] = hv;
      h_bf[0][b * 264 + c] = f2bf(hv);
    }
  }
  float bh_r[2], bh_z[2], bh_n[2];
  #pragma unroll
  for (int i = 0; i < 2; i++){
    int c = (wave*2 + i)*16 + ln16;
    bh_r[i] = bf2f(bhh[dir*768 + c]);
    bh_z[i] = bf2f(bhh[dir*768 + 256 + c]);
    bh_n[i] = bf2f(bhh[dir*768 + 512 + c]);
  }

  // prefetch first step's xp
  int tl = dir ? (CT-1) : 0;
  bf16x8 c_rz0 = *(const bf16x8*)(rzbase + (long)tl*RZ_TL);
  bf16x8 c_rz1 = *(const bf16x8*)(rzbase + (long)tl*RZ_TL + 8);
  bf16x8 c_n   = *(const bf16x8*)(nbase  + (long)tl*N_TL);
  __syncthreads();

  int p = 0;
  for (int ss = 0; ss < CT; ss++){
    // prefetch next step's xp (registers; ~full step of latency cover)
    int tln = (ss == CT-1) ? tl : (dir ? tl-1 : tl+1);
    bf16x8 n_rz0 = *(const bf16x8*)(rzbase + (long)tln*RZ_TL);
    bf16x8 n_rz1 = *(const bf16x8*)(rzbase + (long)tln*RZ_TL + 8);
    bf16x8 n_n   = *(const bf16x8*)(nbase  + (long)tln*N_TL);

    bf16x8 af[8];
    #pragma unroll
    for (int kt = 0; kt < 8; kt++)
      af[kt] = *(bf16x8*)&h_bf[p][ln16 * 264 + kt*32 + quad*8];

    f32x4 ar[2], az[2], an[2];
    #pragma unroll
    for (int i = 0; i < 2; i++){
      ar[i] = (f32x4){0.f,0.f,0.f,0.f};
      az[i] = (f32x4){0.f,0.f,0.f,0.f};
      an[i] = (f32x4){0.f,0.f,0.f,0.f};
    }
    // z,n streamed with 2-deep prefetch
    bf16x8 wzb[2][2], wnb[2][2];
    wzb[0][0] = *(const bf16x8*)(WzP[0]);      wzb[0][1] = *(const bf16x8*)(WzP[1]);
    wnb[0][0] = *(const bf16x8*)(WnP[0]);      wnb[0][1] = *(const bf16x8*)(WnP[1]);
    wzb[1][0] = *(const bf16x8*)(WzP[0] + 32); wzb[1][1] = *(const bf16x8*)(WzP[1] + 32);
    wnb[1][0] = *(const bf16x8*)(WnP[0] + 32); wnb[1][1] = *(const bf16x8*)(WnP[1] + 32);
    #pragma unroll
    for (int kt = 0; kt < 8; kt++){
      bf16x8 z0 = wzb[kt&1][0], z1 = wzb[kt&1][1];
      bf16x8 nn0 = wnb[kt&1][0], nn1 = wnb[kt&1][1];
      if (kt < 6){
        wzb[kt&1][0] = *(const bf16x8*)(WzP[0] + (kt+2)*32);
        wzb[kt&1][1] = *(const bf16x8*)(WzP[1] + (kt+2)*32);
        wnb[kt&1][0] = *(const bf16x8*)(WnP[0] + (kt+2)*32);
        wnb[kt&1][1] = *(const bf16x8*)(WnP[1] + (kt+2)*32);
      }
      ar[0] = __builtin_amdgcn_mfma_f32_16x16x32_bf16(af[kt], wr[0][kt], ar[0], 0, 0, 0);
      az[0] = __builtin_amdgcn_mfma_f32_16x16x32_bf16(af[kt], z0,        az[0], 0, 0, 0);
      an[0] = __builtin_amdgcn_mfma_f32_16x16x32_bf16(af[kt], nn0,       an[0], 0, 0, 0);
      ar[1] = __builtin_amdgcn_mfma_f32_16x16x32_bf16(af[kt], wr[1][kt], ar[1], 0, 0, 0);
      az[1] = __builtin_amdgcn_mfma_f32_16x16x32_bf16(af[kt], z1,        az[1], 0, 0, 0);
      an[1] = __builtin_amdgcn_mfma_f32_16x16x32_bf16(af[kt], nn1,       an[1], 0, 0, 0);
    }

    #pragma unroll
    for (int i = 0; i < 2; i++){
      int c = (wave*2 + i)*16 + ln16;
      #pragma unroll
      for (int r = 0; r < 4; r++){
        float xr = bf2f((unsigned short)(i ? c_rz1[r]   : c_rz0[r]));
        float xz = bf2f((unsigned short)(i ? c_rz1[4+r] : c_rz0[4+r]));
        float xn = bf2f((unsigned short)c_n[i*4 + r]);
        float rg = sigm(xr + ar[i][r] + bh_r[i]);
        float zg = sigm(xz + az[i][r] + bh_z[i]);
        float ng = tanh_f(xn + rg * (an[i][r] + bh_n[i]));
        float hnew = (1.f - zg) * ng + zg * h_old[i][r];
        h_old[i][r] = hnew;
        unsigned short hb = f2bf(hnew);
        int b = b0 + quad*4 + r;
        h_bf[1-p][(quad*4 + r) * 264 + c] = hb;
        long oidx = out_full ? (((long)(t0 + tl) * 256 + b) * 512 + dir*256 + c)
                             : (((long)tl * 256 + b) * 256 + c);
        outp[oidx] = hb;
      }
    }
    __syncthreads();
    p ^= 1;
    tl = tln;
    c_rz0 = n_rz0; c_rz1 = n_rz1; c_n = n_n;
  }

  #pragma unroll
  for (int i = 0; i < 2; i++){
    int c = (wave*2 + i)*16 + ln16;
    #pragma unroll
    for (int r = 0; r < 4; r++)
      hstate[((long)dir*256 + b0 + quad*4 + r)*256 + c] = h_old[i][r];
  }
}

// ------- FC1 per-chunk split-K, both dirs (grid.y): fc1acc += h2[dir] @ W1_dir-slice -------
__global__ __launch_bounds__(256) void k_fc1_chunk(const unsigned short* __restrict__ h2,
                                                   const void* __restrict__ W1,
                                                   const unsigned* __restrict__ w1f,
                                                   int t0f, int t0b,
                                                   float* __restrict__ fc1acc){
  int dir = blockIdx.y;
  const unsigned short* h2d = h2 + (long)dir * CROWS * 256;
  int t0 = dir ? t0b : t0f;
  int dircol = dir * 256;
  int mb = blockIdx.x & 3, kb = blockIdx.x >> 2;
  int wave = threadIdx.x >> 6, lane = threadIdx.x & 63;
  int ln16 = lane & 15, quad = lane >> 4;
  int w1fp32 = (int)*w1f;
  f32x4 acc[8];
  #pragma unroll
  for (int nt = 0; nt < 8; nt++) acc[nt] = (f32x4){0.f,0.f,0.f,0.f};

  for (int tt = 0; tt < 4; tt++){
    int tl = kb*4 + tt;
    const unsigned short* A = h2d + ((long)tl * 256 + mb*64 + wave*16) * 256;
    long bbase = (long)(t0 + tl) * 512 + dircol;
    #pragma unroll
    for (int kt = 0; kt < 8; kt++){
      bf16x8 af = *(const bf16x8*)(A + (long)ln16*256 + kt*32 + quad*8);
      #pragma unroll
      for (int nt = 0; nt < 8; nt++){
        long off = bbase + (long)(nt*16 + ln16)*262144 + kt*32 + quad*8;
        bf16x8 bfr;
        if (w1fp32){
          const float* pp = (const float*)W1 + off;
          #pragma unroll
          for (int j = 0; j < 8; j++) bfr[j] = (short)f2bf(pp[j]);
        } else {
          bfr = *(const bf16x8*)((const unsigned short*)W1 + off);
        }
        acc[nt] = __builtin_amdgcn_mfma_f32_16x16x32_bf16(af, bfr, acc[nt], 0, 0, 0);
      }
    }
  }
  #pragma unroll
  for (int nt = 0; nt < 8; nt++)
    #pragma unroll
    for (int r = 0; r < 4; r++){
      int m = mb*64 + wave*16 + quad*4 + r;
      int n = nt*16 + ln16;
      atomicAdd(&fc1acc[m*128 + n], acc[nt][r]);
    }
}

// ------- final: leaky_relu(fc1acc + b1) @ W2 + b2 -> sigmoid -------
__global__ __launch_bounds__(256) void k_fc2(const float* __restrict__ fc1acc,
                                             const unsigned short* __restrict__ b1,
                                             const unsigned short* __restrict__ W2,
                                             const unsigned short* __restrict__ b2,
                                             const unsigned* __restrict__ flags,
                                             void* __restrict__ out){
  int b = threadIdx.x;
  float s = bf2f(b2[0]);
  for (int j = 0; j < 128; j++){
    float v = fc1acc[b*128 + j] + bf2f(b1[j]);
    v = v > 0.f ? v : 0.01f * v;
    s += v * bf2f(W2[j]);
  }
  float r = sigm(s);
  if (flags[1]) ((float*)out)[b] = r;          // fp32 world -> fp32 output
  else          ((unsigned short*)out)[b] = f2bf(r);
}

extern "C" void kernel_launch(void* const* d_in, const int* in_sizes, int n_in,
                              void* d_out, int out_size, void* d_ws, size_t ws_size,
                              hipStream_t stream) {
  const void* inp  = d_in[0];
  const void* emb  = d_in[1];
  const void* wih0 = d_in[2];
  const void* whh0 = d_in[3];
  const void* bih0 = d_in[4];
  const void* bhh0 = d_in[5];
  const void* wih1 = d_in[6];
  const void* whh1 = d_in[7];
  const void* bih1 = d_in[8];
  const void* bhh1 = d_in[9];
  const void* W1   = d_in[10];
  const void* b1   = d_in[11];
  const void* W2   = d_in[12];
  const void* b2   = d_in[13];
  unsigned short* out = (unsigned short*)d_out;

  const int expect[14] = {131072, 8320, 196608, 393216, 1536, 1536,
                          786432, 393216, 1536, 1536, 33554432, 128, 128, 1};
  for (int i = 0; i < 14 && i < n_in; i++){
    if (in_sizes[i] != expect[i]){
      k_sentinel<<<1, 256, 0, stream>>>(out, 4.0f * (600.0f + i));
      return;
    }
  }

  // workspace layout (bytes)
  const size_t OFF_X    = 0;                       // x    [131072*128] bf16
  const size_t OFF_H1   = 33554432ul;              // h1   [131072*512] bf16
  const size_t OFF_XPRZ = 167772160ul;             // xprz [2][RZ_DIR] bf16 (33.6 MB)
  const size_t OFF_XPN  = 201326592ul;             // xpn  [2][N_DIR]  bf16 (16.8 MB)
  const size_t OFF_H2   = 218103808ul;             // h2   [2][16384*256] bf16 (16.8 MB)
  const size_t OFF_ST   = 234881024ul;             // hstate [2*256*256] f32
  const size_t OFF_FC   = 235405312ul;             // fc1acc [256*128] f32
  const size_t OFF_FLAG = 235536384ul;             // 16 flag words
  const size_t OFF_P    = 235536448ul;             // converted bf16 params (~3.6 MB)
  unsigned short* P;
  const size_t PO_EMB  = 0;        // 8320
  const size_t PO_WIH0 = 8320;     // 196608
  const size_t PO_WHH0 = 204928;   // 393216
  const size_t PO_BIH0 = 598144;   // 1536
  const size_t PO_BHH0 = 599680;   // 1536
  const size_t PO_WIH1 = 601216;   // 786432
  const size_t PO_WHH1 = 1387648;  // 393216
  const size_t PO_BIH1 = 1780864;  // 1536
  const size_t PO_BHH1 = 1782400;  // 1536
  const size_t PO_B1   = 1783936;  // 128
  const size_t PO_W2   = 1784064;  // 128
  const size_t PO_B2   = 1784192;  // 1 (+pad)
  const size_t NEED    = OFF_P + 2*1784200ul;

  if (ws_size < NEED) {
    k_sentinel<<<1, 256, 0, stream>>>(out, (float)(ws_size >> 20));
    return;
  }

  char* ws = (char*)d_ws;
  unsigned short* x    = (unsigned short*)(ws + OFF_X);
  unsigned short* h1   = (unsigned short*)(ws + OFF_H1);
  unsigned short* xprz = (unsigned short*)(ws + OFF_XPRZ);
  unsigned short* xpn  = (unsigned short*)(ws + OFF_XPN);
  unsigned short* h2   = (unsigned short*)(ws + OFF_H2);
  unsigned short* h2b  = h2 + (long)CROWS*256;
  float*          hst  = (float*)(ws + OFF_ST);
  float*          fc1a = (float*)(ws + OFF_FC);
  unsigned*       flg  = (unsigned*)(ws + OFF_FLAG);
  P = (unsigned short*)(ws + OFF_P);

  hipMemsetAsync(flg, 0, 64, stream);

  // ---- dtype probes ----
  k_probe_f<<<1,256,0,stream>>>((const unsigned short*)emb,  8320,     flg+1);
  k_probe_f<<<1,256,0,stream>>>((const unsigned short*)wih0, 196608,   flg+2);
  k_probe_f<<<1,256,0,stream>>>((const unsigned short*)whh0, 393216,   flg+3);
  k_probe_f<<<1,256,0,stream>>>((const unsigned short*)bih0, 1536,     flg+4);
  k_probe_f<<<1,256,0,stream>>>((const unsigned short*)bhh0, 1536,     flg+5);
  k_probe_f<<<1,256,0,stream>>>((const unsigned short*)wih1, 786432,   flg+6);
  k_probe_f<<<1,256,0,stream>>>((const unsigned short*)whh1, 393216,   flg+7);
  k_probe_f<<<1,256,0,stream>>>((const unsigned short*)bih1, 1536,     flg+8);
  k_probe_f<<<1,256,0,stream>>>((const unsigned short*)bhh1, 1536,     flg+9);
  k_probe_f<<<1,256,0,stream>>>((const unsigned short*)b1,   128,      flg+10);
  k_probe_f<<<1,256,0,stream>>>((const unsigned short*)W2,   128,      flg+11);
  k_probe_f<<<1,256,0,stream>>>((const unsigned short*)b2,   1,        flg+12);
  k_probe_f<<<1,256,0,stream>>>((const unsigned short*)W1,   33554432, flg+13);
  k_probe_i<<<1,256,0,stream>>>((const int*)inp, 131072, flg+14);

  // ---- convert params to bf16 ----
  k_convert<<<64,256,0,stream>>>(emb,  8320,   flg+1,  P+PO_EMB);
  k_convert<<<64,256,0,stream>>>(wih0, 196608, flg+2,  P+PO_WIH0);
  k_convert<<<64,256,0,stream>>>(whh0, 393216, flg+3,  P+PO_WHH0);
  k_convert<<<8, 256,0,stream>>>(bih0, 1536,   flg+4,  P+PO_BIH0);
  k_convert<<<8, 256,0,stream>>>(bhh0, 1536,   flg+5,  P+PO_BHH0);
  k_convert<<<64,256,0,stream>>>(wih1, 786432, flg+6,  P+PO_WIH1);
  k_convert<<<64,256,0,stream>>>(whh1, 393216, flg+7,  P+PO_WHH1);
  k_convert<<<8, 256,0,stream>>>(bih1, 1536,   flg+8,  P+PO_BIH1);
  k_convert<<<8, 256,0,stream>>>(bhh1, 1536,   flg+9,  P+PO_BHH1);
  k_convert<<<1, 256,0,stream>>>(b1,   128,    flg+10, P+PO_B1);
  k_convert<<<1, 256,0,stream>>>(W2,   128,    flg+11, P+PO_W2);
  k_convert<<<1, 256,0,stream>>>(b2,   1,      flg+12, P+PO_B2);

  k_embed<<<MM*16/256, 256, 0, stream>>>(P+PO_EMB, inp, flg+14, x);

  // ---- layer 0 ----
  hipMemsetAsync(hst, 0, 2*256*256*sizeof(float), stream);
  for (int c = 0; c < NCH; c++){
    int t0f = c * CT, t0b = (NCH - 1 - c) * CT;
    k_gemm_chunk<128><<<dim3(CROWS/128, 6, 2), 256, 0, stream>>>(x, P+PO_WIH0, P+PO_BIH0, xprz, xpn, t0f, t0b);
    k_gru_chunk<<<32, 512, 0, stream>>>(xprz, xpn, P+PO_WHH0, P+PO_BHH0, hst, h1, h1, 1, t0f, t0b);
  }

  // ---- layer 1 (+ fused FC1 accumulation) ----
  hipMemsetAsync(hst, 0, 2*256*256*sizeof(float), stream);
  hipMemsetAsync(fc1a, 0, 256*128*sizeof(float), stream);
  for (int c = 0; c < NCH; c++){
    int t0f = c * CT, t0b = (NCH - 1 - c) * CT;
    k_gemm_chunk<512><<<dim3(CROWS/128, 6, 2), 256, 0, stream>>>(h1, P+PO_WIH1, P+PO_BIH1, xprz, xpn, t0f, t0b);
    k_gru_chunk<<<32, 512, 0, stream>>>(xprz, xpn, P+PO_WHH1, P+PO_BHH1, hst, h2, h2b, 0, t0f, t0b);
    k_fc1_chunk<<<dim3(64, 2), 256, 0, stream>>>(h2, W1, flg+13, t0f, t0b, fc1a);
  }

  k_fc2<<<1, 256, 0, stream>>>(fc1a, P+PO_B1, P+PO_W2, P+PO_B2, flg, d_out);
}

// Round 7
// 6555.021 us; speedup vs baseline: 1.4061x; 1.0780x over previous
//
#include <hip/hip_runtime.h>
#include <hip/hip_bf16.h>
#include <stdint.h>

// Problem dims
#define BB 256
#define TT 512
#define EE 128
#define HH 256
#define MM (TT*BB)       // 131072 rows total
#define CT 64            // timesteps per chunk
#define NCH (TT/CT)      // 8 chunks
#define CROWS (CT*BB)    // 16384 rows per chunk
// swizzled xp sizes (shorts)
#define RZ_DIR 8388608   // 64*16*8*64*16
#define RZ_TL  131072    // 16*8*64*16
#define N_DIR  4194304   // 64*16*8*64*8
#define N_TL   65536
// GRU dynamic LDS: n-weights [256][256] + h double buffer [2][16*264]
#define WN_SH   65536                 // shorts
#define HBUF_SH (16*264)              // shorts per buffer
#define GRU_SMEM ((WN_SH + 2*HBUF_SH) * 2)   // bytes = 147968

typedef __attribute__((ext_vector_type(8))) short bf16x8;
typedef __attribute__((ext_vector_type(4))) float f32x4;

__device__ __forceinline__ float bf2f(unsigned short u){
  union { unsigned int i; float f; } v; v.i = ((unsigned int)u) << 16; return v.f;
}
__device__ __forceinline__ unsigned short f2bf(float f){
  union { float f; unsigned int i; } v; v.f = f;
  unsigned int u = v.i;
  unsigned int r = (u + 0x7FFFu + ((u >> 16) & 1u)) >> 16;
  return (unsigned short)r;
}
__device__ __forceinline__ float sigm(float x){ return 1.f / (1.f + __expf(-x)); }
__device__ __forceinline__ float tanh_f(float x){
  float e2 = __expf(2.f * x);
  return 1.f - 2.f / (e2 + 1.f);
}

// -------- sentinel --------
__global__ void k_sentinel(unsigned short* out, float v){ out[threadIdx.x] = f2bf(v); }

// -------- dtype probe: is this float tensor fp32 (vs bf16)? --------
__global__ void k_probe_f(const unsigned short* __restrict__ buf, int n,
                          unsigned* __restrict__ flagw){
  __shared__ int cnt;
  if (threadIdx.x == 0) cnt = 0;
  __syncthreads();
  int scanw = n < 4096 ? n : 4096;
  int bad = 0;
  for (int i = threadIdx.x; i < scanw; i += 256){
    unsigned short u = buf[i];
    unsigned e = (u >> 7) & 0xFF;
    if (u != 0 && (e < 0x60 || e == 0xFF)) bad++;
  }
  atomicAdd(&cnt, bad);
  __syncthreads();
  if (threadIdx.x == 0) *flagw = (cnt * 8 > scanw) ? 1u : 0u;
}

// -------- int width probe: int64 iff odd int32 words are (almost) all zero --------
__global__ void k_probe_i(const int* __restrict__ buf, int n, unsigned* __restrict__ flagw){
  __shared__ int cnt;
  if (threadIdx.x == 0) cnt = 0;
  __syncthreads();
  int scan = n < 1024 ? n : 1024;
  int nz = 0;
  for (int i = threadIdx.x; i < scan; i += 256)
    if ((i & 1) && buf[i] != 0) nz++;
  atomicAdd(&cnt, nz);
  __syncthreads();
  if (threadIdx.x == 0) *flagw = (cnt < 10) ? 1u : 0u;
}

// -------- convert a float tensor (fp32 or bf16 per flag) to bf16 dst --------
__global__ __launch_bounds__(256) void k_convert(const void* __restrict__ src, int n,
                                                 const unsigned* __restrict__ flagw,
                                                 unsigned short* __restrict__ dst){
  int fp32 = (int)*flagw;
  int i0 = blockIdx.x * 256 + threadIdx.x;
  int stride = gridDim.x * 256;
  if (fp32){
    const float* s = (const float*)src;
    for (int i = i0; i < n; i += stride) dst[i] = f2bf(s[i]);
  } else {
    const unsigned short* s = (const unsigned short*)src;
    for (int i = i0; i < n; i += stride) dst[i] = s[i];
  }
}

// ---------------- embed: x[t*B+b][e] = embc[inputs[b][t]][e] (bf16) ----------------
__global__ __launch_bounds__(256) void k_embed(const unsigned short* __restrict__ embc,
                                               const void* __restrict__ inputs,
                                               const unsigned* __restrict__ i64f,
                                               unsigned short* __restrict__ x){
  int c = blockIdx.x * 256 + threadIdx.x;  // 16B chunk id; total = MM*16
  int e8 = (c & 15) * 8;
  int tb = c >> 4;
  int t = tb >> 8;
  int b = tb & 255;
  long k = (long)b * TT + t;
  int idx = (*i64f) ? ((const int*)inputs)[k * 2] : ((const int*)inputs)[k];
  idx = idx < 0 ? 0 : (idx > 64 ? 64 : idx);
  *(bf16x8*)(x + (long)tb * EE + e8) = *(const bf16x8*)(embc + (long)idx * EE + e8);
}

// ------- chunk xp GEMM, both dirs (grid.z), epilogue writes GRU-swizzled xp -------
// xp_rz record (per tl,bg,w,lane): 16 shorts = [i0: r gate r0..3 | z gate r0..3][i1: same]
// xp_n  record: 8 shorts = [i0: n gate r0..3][i1: r0..3]
template<int K>
__global__ __launch_bounds__(256) void k_gemm_chunk(const unsigned short* __restrict__ A,
                                                    const unsigned short* __restrict__ W,
                                                    const unsigned short* __restrict__ bias,
                                                    unsigned short* __restrict__ xprz,
                                                    unsigned short* __restrict__ xpn,
                                                    int t0f, int t0b){
  __shared__ __align__(16) unsigned short As[128 * 72];
  __shared__ __align__(16) unsigned short Bs[128 * 72];
  int dir = blockIdx.z;
  const unsigned short* Ad = A + (long)(dir ? t0b : t0f) * 256 * K;
  const unsigned short* Wd = W + (long)dir * 768 * K;
  const unsigned short* bd = bias + dir * 768;
  unsigned short* rzd = xprz + (long)dir * RZ_DIR;
  unsigned short* nd  = xpn  + (long)dir * N_DIR;

  int tid = threadIdx.x;
  long m0 = (long)blockIdx.x * 128;
  int  n0 = blockIdx.y * 128;
  int wave = tid >> 6, lane = tid & 63;
  int wm = (wave & 1) * 64, wn = (wave >> 1) * 64;
  int ln16 = lane & 15, quad = lane >> 4;
  f32x4 acc[4][4];
  #pragma unroll
  for (int i = 0; i < 4; i++)
    #pragma unroll
    for (int j = 0; j < 4; j++) acc[i][j] = (f32x4){0.f,0.f,0.f,0.f};

  for (int k0 = 0; k0 < K; k0 += 64){
    #pragma unroll
    for (int i = 0; i < 4; i++){
      int c = tid + 256 * i;        // 1024 chunks of 8 bf16
      int row = c >> 3, koff = (c & 7) * 8;
      *(bf16x8*)&As[row * 72 + koff] = *(const bf16x8*)&Ad[(m0 + row) * K + k0 + koff];
      *(bf16x8*)&Bs[row * 72 + koff] = *(const bf16x8*)&Wd[(long)(n0 + row) * K + k0 + koff];
    }
    __syncthreads();
    #pragma unroll
    for (int kk = 0; kk < 64; kk += 32){
      bf16x8 af[4], bfr[4];
      #pragma unroll
      for (int mi = 0; mi < 4; mi++) af[mi]  = *(bf16x8*)&As[(wm + mi*16 + ln16) * 72 + kk + quad*8];
      #pragma unroll
      for (int nj = 0; nj < 4; nj++) bfr[nj] = *(bf16x8*)&Bs[(wn + nj*16 + ln16) * 72 + kk + quad*8];
      #pragma unroll
      for (int mi = 0; mi < 4; mi++)
        #pragma unroll
        for (int nj = 0; nj < 4; nj++)
          acc[mi][nj] = __builtin_amdgcn_mfma_f32_16x16x32_bf16(af[mi], bfr[nj], acc[mi][nj], 0, 0, 0);
    }
    __syncthreads();
  }
  // swizzled epilogue
  #pragma unroll
  for (int mi = 0; mi < 4; mi++)
    #pragma unroll
    for (int nj = 0; nj < 4; nj++){
      int n = n0 + wn + nj*16 + ln16;       // 0..767 within dir
      int g = n >> 8, c = n & 255;
      int w = c >> 5, ii = (c >> 4) & 1;
      float bv = bf2f(bd[n]);
      #pragma unroll
      for (int r = 0; r < 4; r++){
        long m = m0 + wm + mi*16 + quad*4 + r;
        int tl = (int)(m >> 8);
        int bgx = ((int)m & 255) >> 4;      // m&15 == quad*4+r
        long rec = (((long)tl*16 + bgx)*8 + w)*64 + quad*16 + ln16;
        unsigned short val = f2bf(acc[mi][nj][r] + bv);
        if (g < 2) rzd[rec*16 + ii*8 + g*4 + r] = val;
        else       nd [rec*8  + ii*4 + r]       = val;
      }
    }
}

// ---------------- GRU recurrence over one 64-step chunk, both dirs ----------------
// grid = 32 blocks (dir = blk>>4, batch group of 16 = blk&15), 512 threads (8 waves).
// __launch_bounds__(512,2): VGPR cap 256 -> r,z weights genuinely register-resident
// (128 VGPR); n-gate weights staged in LDS once per chunk (128 KB). Zero per-step
// global weight traffic. xp read as 3 coalesced dwordx4/lane/step, prefetched 1 step.
__global__ __launch_bounds__(512, 2) void k_gru_chunk(const unsigned short* __restrict__ xprz,
                                                      const unsigned short* __restrict__ xpn,
                                                      const unsigned short* __restrict__ whh,
                                                      const unsigned short* __restrict__ bhh,
                                                      float* __restrict__ hstate,  // [2][256][256]
                                                      unsigned short* __restrict__ outf,
                                                      unsigned short* __restrict__ outb,
                                                      int out_full, int t0f, int t0b){
  extern __shared__ __align__(16) unsigned short smem[];   // [WN_SH] + [2][HBUF_SH]
  unsigned short* wn_lds = smem;
  unsigned short* hbuf   = smem + WN_SH;

  int tid = threadIdx.x;
  int dir = blockIdx.x >> 4;
  int bg  = blockIdx.x & 15;
  int b0  = bg * 16;
  int wave = tid >> 6, lane = tid & 63;
  int ln16 = lane & 15, quad = lane >> 4;
  unsigned short* outp = dir ? outb : outf;
  int t0 = dir ? t0b : t0f;

  const unsigned short* rzbase = xprz + (long)dir * RZ_DIR + ((long)(bg*8 + wave)*64 + lane) * 16;
  const unsigned short* nbase  = xpn  + (long)dir * N_DIR  + ((long)(bg*8 + wave)*64 + lane) * 8;

  // stage n-gate weights into LDS: rows c=0..255 -> whh[dir*768+512+c][0..255]
  for (int v = tid; v < 256*32; v += 512){
    int c = v >> 5, k8 = (v & 31) * 8;
    *(bf16x8*)&wn_lds[c*256 + k8] = *(const bf16x8*)&whh[((long)(dir*768 + 512 + c))*256 + k8];
  }

  // r,z weight fragments resident in VGPRs (128)
  bf16x8 wr[2][8], wz[2][8];
  #pragma unroll
  for (int i = 0; i < 2; i++){
    int c = (wave*2 + i)*16 + ln16;
    const unsigned short* Wb = whh + ((long)(dir*768 + c)) * 256 + quad*8;
    #pragma unroll
    for (int kt = 0; kt < 8; kt++){
      wr[i][kt] = *(const bf16x8*)(Wb + kt*32);
      wz[i][kt] = *(const bf16x8*)(Wb + 256*256 + kt*32);
    }
  }

  // carried state -> regs + LDS buffer 0
  float h_old[2][4];
  #pragma unroll
  for (int i = 0; i < 2; i++){
    int c = (wave*2 + i)*16 + ln16;
    #pragma unroll
    for (int r = 0; r < 4; r++){
      int b = quad*4 + r;
      float hv = hstate[((long)dir*256 + b0 + b)*256 + c];
      h_old[i][r] = hv;
      hbuf[b * 264 + c] = f2bf(hv);
    }
  }
  float bh_r[2], bh_z[2], bh_n[2];
  #pragma unroll
  for (int i = 0; i < 2; i++){
    int c = (wave*2 + i)*16 + ln16;
    bh_r[i] = bf2f(bhh[dir*768 + c]);
    bh_z[i] = bf2f(bhh[dir*768 + 256 + c]);
    bh_n[i] = bf2f(bhh[dir*768 + 512 + c]);
  }

  int wn_row0 = (wave*2 + 0)*16 + ln16;     // LDS row for i=0 fragments
  int wn_row1 = (wave*2 + 1)*16 + ln16;

  // prefetch first step's xp
  int tl = dir ? (CT-1) : 0;
  bf16x8 c_rz0 = *(const bf16x8*)(rzbase + (long)tl*RZ_TL);
  bf16x8 c_rz1 = *(const bf16x8*)(rzbase + (long)tl*RZ_TL + 8);
  bf16x8 c_n   = *(const bf16x8*)(nbase  + (long)tl*N_TL);
  __syncthreads();

  int p = 0;
  for (int ss = 0; ss < CT; ss++){
    // prefetch next step's xp
    int tln = (ss == CT-1) ? tl : (dir ? tl-1 : tl+1);
    bf16x8 n_rz0 = *(const bf16x8*)(rzbase + (long)tln*RZ_TL);
    bf16x8 n_rz1 = *(const bf16x8*)(rzbase + (long)tln*RZ_TL + 8);
    bf16x8 n_n   = *(const bf16x8*)(nbase  + (long)tln*N_TL);

    unsigned short* hb_cur = hbuf + p*HBUF_SH;
    unsigned short* hb_nxt = hbuf + (1-p)*HBUF_SH;

    f32x4 ar[2], az[2], an[2];
    #pragma unroll
    for (int i = 0; i < 2; i++){
      ar[i] = (f32x4){0.f,0.f,0.f,0.f};
      az[i] = (f32x4){0.f,0.f,0.f,0.f};
      an[i] = (f32x4){0.f,0.f,0.f,0.f};
    }

    // 2-deep pipelined LDS reads: h A-fragment + n-gate B-fragments
    bf16x8 afb[2], wnb[2][2];
    afb[0]    = *(bf16x8*)&hb_cur[ln16*264 + quad*8];
    wnb[0][0] = *(bf16x8*)&wn_lds[wn_row0*256 + quad*8];
    wnb[0][1] = *(bf16x8*)&wn_lds[wn_row1*256 + quad*8];
    #pragma unroll
    for (int kt = 0; kt < 8; kt++){
      int cur = kt & 1, nxt = cur ^ 1;
      if (kt < 7){
        afb[nxt]    = *(bf16x8*)&hb_cur[ln16*264 + (kt+1)*32 + quad*8];
        wnb[nxt][0] = *(bf16x8*)&wn_lds[wn_row0*256 + (kt+1)*32 + quad*8];
        wnb[nxt][1] = *(bf16x8*)&wn_lds[wn_row1*256 + (kt+1)*32 + quad*8];
      }
      ar[0] = __builtin_amdgcn_mfma_f32_16x16x32_bf16(afb[cur], wr[0][kt], ar[0], 0, 0, 0);
      az[0] = __builtin_amdgcn_mfma_f32_16x16x32_bf16(afb[cur], wz[0][kt], az[0], 0, 0, 0);
      an[0] = __builtin_amdgcn_mfma_f32_16x16x32_bf16(afb[cur], wnb[cur][0], an[0], 0, 0, 0);
      ar[1] = __builtin_amdgcn_mfma_f32_16x16x32_bf16(afb[cur], wr[1][kt], ar[1], 0, 0, 0);
      az[1] = __builtin_amdgcn_mfma_f32_16x16x32_bf16(afb[cur], wz[1][kt], az[1], 0, 0, 0);
      an[1] = __builtin_amdgcn_mfma_f32_16x16x32_bf16(afb[cur], wnb[cur][1], an[1], 0, 0, 0);
    }

    #pragma unroll
    for (int i = 0; i < 2; i++){
      int c = (wave*2 + i)*16 + ln16;
      #pragma unroll
      for (int r = 0; r < 4; r++){
        float xr = bf2f((unsigned short)(i ? c_rz1[r]   : c_rz0[r]));
        float xz = bf2f((unsigned short)(i ? c_rz1[4+r] : c_rz0[4+r]));
        float xn = bf2f((unsigned short)c_n[i*4 + r]);
        float rg = sigm(xr + ar[i][r] + bh_r[i]);
        float zg = sigm(xz + az[i][r] + bh_z[i]);
        float ng = tanh_f(xn + rg * (an[i][r] + bh_n[i]));
        float hnew = (1.f - zg) * ng + zg * h_old[i][r];
        h_old[i][r] = hnew;
        unsigned short hb = f2bf(hnew);
        int b = b0 + quad*4 + r;
        hb_nxt[(quad*4 + r) * 264 + c] = hb;
        long oidx = out_full ? (((long)(t0 + tl) * 256 + b) * 512 + dir*256 + c)
                             : (((long)tl * 256 + b) * 256 + c);
        outp[oidx] = hb;
      }
    }
    __syncthreads();
    p ^= 1;
    tl = tln;
    c_rz0 = n_rz0; c_rz1 = n_rz1; c_n = n_n;
  }

  #pragma unroll
  for (int i = 0; i < 2; i++){
    int c = (wave*2 + i)*16 + ln16;
    #pragma unroll
    for (int r = 0; r < 4; r++)
      hstate[((long)dir*256 + b0 + quad*4 + r)*256 + c] = h_old[i][r];
  }
}

// ------- FC1 per-chunk split-K, both dirs (grid.y): fc1acc += h2[dir] @ W1_dir-slice -------
__global__ __launch_bounds__(256) void k_fc1_chunk(const unsigned short* __restrict__ h2,
                                                   const void* __restrict__ W1,
                                                   const unsigned* __restrict__ w1f,
                                                   int t0f, int t0b,
                                                   float* __restrict__ fc1acc){
  int dir = blockIdx.y;
  const unsigned short* h2d = h2 + (long)dir * CROWS * 256;
  int t0 = dir ? t0b : t0f;
  int dircol = dir * 256;
  int mb = blockIdx.x & 3, kb = blockIdx.x >> 2;
  int wave = threadIdx.x >> 6, lane = threadIdx.x & 63;
  int ln16 = lane & 15, quad = lane >> 4;
  int w1fp32 = (int)*w1f;
  f32x4 acc[8];
  #pragma unroll
  for (int nt = 0; nt < 8; nt++) acc[nt] = (f32x4){0.f,0.f,0.f,0.f};

  for (int tt = 0; tt < 4; tt++){
    int tl = kb*4 + tt;
    const unsigned short* A = h2d + ((long)tl * 256 + mb*64 + wave*16) * 256;
    long bbase = (long)(t0 + tl) * 512 + dircol;
    #pragma unroll
    for (int kt = 0; kt < 8; kt++){
      bf16x8 af = *(const bf16x8*)(A + (long)ln16*256 + kt*32 + quad*8);
      #pragma unroll
      for (int nt = 0; nt < 8; nt++){
        long off = bbase + (long)(nt*16 + ln16)*262144 + kt*32 + quad*8;
        bf16x8 bfr;
        if (w1fp32){
          const float* pp = (const float*)W1 + off;
          #pragma unroll
          for (int j = 0; j < 8; j++) bfr[j] = (short)f2bf(pp[j]);
        } else {
          bfr = *(const bf16x8*)((const unsigned short*)W1 + off);
        }
        acc[nt] = __builtin_amdgcn_mfma_f32_16x16x32_bf16(af, bfr, acc[nt], 0, 0, 0);
      }
    }
  }
  #pragma unroll
  for (int nt = 0; nt < 8; nt++)
    #pragma unroll
    for (int r = 0; r < 4; r++){
      int m = mb*64 + wave*16 + quad*4 + r;
      int n = nt*16 + ln16;
      atomicAdd(&fc1acc[m*128 + n], acc[nt][r]);
    }
}

// ------- final: leaky_relu(fc1acc + b1) @ W2 + b2 -> sigmoid -------
__global__ __launch_bounds__(256) void k_fc2(const float* __restrict__ fc1acc,
                                             const unsigned short* __restrict__ b1,
                                             const unsigned short* __restrict__ W2,
                                             const unsigned short* __restrict__ b2,
                                             const unsigned* __restrict__ flags,
                                             void* __restrict__ out){
  int b = threadIdx.x;
  float s = bf2f(b2[0]);
  for (int j = 0; j < 128; j++){
    float v = fc1acc[b*128 + j] + bf2f(b1[j]);
    v = v > 0.f ? v : 0.01f * v;
    s += v * bf2f(W2[j]);
  }
  float r = sigm(s);
  if (flags[1]) ((float*)out)[b] = r;          // fp32 world -> fp32 output
  else          ((unsigned short*)out)[b] = f2bf(r);
}

extern "C" void kernel_launch(void* const* d_in, const int* in_sizes, int n_in,
                              void* d_out, int out_size, void* d_ws, size_t ws_size,
                              hipStream_t stream) {
  const void* inp  = d_in[0];
  const void* emb  = d_in[1];
  const void* wih0 = d_in[2];
  const void* whh0 = d_in[3];
  const void* bih0 = d_in[4];
  const void* bhh0 = d_in[5];
  const void* wih1 = d_in[6];
  const void* whh1 = d_in[7];
  const void* bih1 = d_in[8];
  const void* bhh1 = d_in[9];
  const void* W1   = d_in[10];
  const void* b1   = d_in[11];
  const void* W2   = d_in[12];
  const void* b2   = d_in[13];
  unsigned short* out = (unsigned short*)d_out;

  const int expect[14] = {131072, 8320, 196608, 393216, 1536, 1536,
                          786432, 393216, 1536, 1536, 33554432, 128, 128, 1};
  for (int i = 0; i < 14 && i < n_in; i++){
    if (in_sizes[i] != expect[i]){
      k_sentinel<<<1, 256, 0, stream>>>(out, 4.0f * (600.0f + i));
      return;
    }
  }

  // allow >64KB dynamic LDS for the GRU kernel (idempotent host-side attr, not a stream op)
  static int smem_set = 0;
  if (!smem_set){
    hipFuncSetAttribute((const void*)k_gru_chunk,
                        hipFuncAttributeMaxDynamicSharedMemorySize, GRU_SMEM);
    smem_set = 1;
  }

  // workspace layout (bytes)
  const size_t OFF_X    = 0;                       // x    [131072*128] bf16
  const size_t OFF_H1   = 33554432ul;              // h1   [131072*512] bf16
  const size_t OFF_XPRZ = 167772160ul;             // xprz [2][RZ_DIR] bf16 (33.6 MB)
  const size_t OFF_XPN  = 201326592ul;             // xpn  [2][N_DIR]  bf16 (16.8 MB)
  const size_t OFF_H2   = 218103808ul;             // h2   [2][16384*256] bf16 (16.8 MB)
  const size_t OFF_ST   = 234881024ul;             // hstate [2*256*256] f32
  const size_t OFF_FC   = 235405312ul;             // fc1acc [256*128] f32
  const size_t OFF_FLAG = 235536384ul;             // 16 flag words
  const size_t OFF_P    = 235536448ul;             // converted bf16 params (~3.6 MB)
  unsigned short* P;
  const size_t PO_EMB  = 0;        // 8320
  const size_t PO_WIH0 = 8320;     // 196608
  const size_t PO_WHH0 = 204928;   // 393216
  const size_t PO_BIH0 = 598144;   // 1536
  const size_t PO_BHH0 = 599680;   // 1536
  const size_t PO_WIH1 = 601216;   // 786432
  const size_t PO_WHH1 = 1387648;  // 393216
  const size_t PO_BIH1 = 1780864;  // 1536
  const size_t PO_BHH1 = 1782400;  // 1536
  const size_t PO_B1   = 1783936;  // 128
  const size_t PO_W2   = 1784064;  // 128
  const size_t PO_B2   = 1784192;  // 1 (+pad)
  const size_t NEED    = OFF_P + 2*1784200ul;

  if (ws_size < NEED) {
    k_sentinel<<<1, 256, 0, stream>>>(out, (float)(ws_size >> 20));
    return;
  }

  char* ws = (char*)d_ws;
  unsigned short* x    = (unsigned short*)(ws + OFF_X);
  unsigned short* h1   = (unsigned short*)(ws + OFF_H1);
  unsigned short* xprz = (unsigned short*)(ws + OFF_XPRZ);
  unsigned short* xpn  = (unsigned short*)(ws + OFF_XPN);
  unsigned short* h2   = (unsigned short*)(ws + OFF_H2);
  unsigned short* h2b  = h2 + (long)CROWS*256;
  float*          hst  = (float*)(ws + OFF_ST);
  float*          fc1a = (float*)(ws + OFF_FC);
  unsigned*       flg  = (unsigned*)(ws + OFF_FLAG);
  P = (unsigned short*)(ws + OFF_P);

  hipMemsetAsync(flg, 0, 64, stream);

  // ---- dtype probes ----
  k_probe_f<<<1,256,0,stream>>>((const unsigned short*)emb,  8320,     flg+1);
  k_probe_f<<<1,256,0,stream>>>((const unsigned short*)wih0, 196608,   flg+2);
  k_probe_f<<<1,256,0,stream>>>((const unsigned short*)whh0, 393216,   flg+3);
  k_probe_f<<<1,256,0,stream>>>((const unsigned short*)bih0, 1536,     flg+4);
  k_probe_f<<<1,256,0,stream>>>((const unsigned short*)bhh0, 1536,     flg+5);
  k_probe_f<<<1,256,0,stream>>>((const unsigned short*)wih1, 786432,   flg+6);
  k_probe_f<<<1,256,0,stream>>>((const unsigned short*)whh1, 393216,   flg+7);
  k_probe_f<<<1,256,0,stream>>>((const unsigned short*)bih1, 1536,     flg+8);
  k_probe_f<<<1,256,0,stream>>>((const unsigned short*)bhh1, 1536,     flg+9);
  k_probe_f<<<1,256,0,stream>>>((const unsigned short*)b1,   128,      flg+10);
  k_probe_f<<<1,256,0,stream>>>((const unsigned short*)W2,   128,      flg+11);
  k_probe_f<<<1,256,0,stream>>>((const unsigned short*)b2,   1,        flg+12);
  k_probe_f<<<1,256,0,stream>>>((const unsigned short*)W1,   33554432, flg+13);
  k_probe_i<<<1,256,0,stream>>>((const int*)inp, 131072, flg+14);

  // ---- convert params to bf16 ----
  k_convert<<<64,256,0,stream>>>(emb,  8320,   flg+1,  P+PO_EMB);
  k_convert<<<64,256,0,stream>>>(wih0, 196608, flg+2,  P+PO_WIH0);
  k_convert<<<64,256,0,stream>>>(whh0, 393216, flg+3,  P+PO_WHH0);
  k_convert<<<8, 256,0,stream>>>(bih0, 1536,   flg+4,  P+PO_BIH0);
  k_convert<<<8, 256,0,stream>>>(bhh0, 1536,   flg+5,  P+PO_BHH0);
  k_convert<<<64,256,0,stream>>>(wih1, 786432, flg+6,  P+PO_WIH1);
  k_convert<<<64,256,0,stream>>>(whh1, 393216, flg+7,  P+PO_WHH1);
  k_convert<<<8, 256,0,stream>>>(bih1, 1536,   flg+8,  P+PO_BIH1);
  k_convert<<<8, 256,0,stream>>>(bhh1, 1536,   flg+9,  P+PO_BHH1);
  k_convert<<<1, 256,0,stream>>>(b1,   128,    flg+10, P+PO_B1);
  k_convert<<<1, 256,0,stream>>>(W2,   128,    flg+11, P+PO_W2);
  k_convert<<<1, 256,0,stream>>>(b2,   1,      flg+12, P+PO_B2);

  k_embed<<<MM*16/256, 256, 0, stream>>>(P+PO_EMB, inp, flg+14, x);

  // ---- layer 0 ----
  hipMemsetAsync(hst, 0, 2*256*256*sizeof(float), stream);
  for (int c = 0; c < NCH; c++){
    int t0f = c * CT, t0b = (NCH - 1 - c) * CT;
    k_gemm_chunk<128><<<dim3(CROWS/128, 6, 2), 256, 0, stream>>>(x, P+PO_WIH0, P+PO_BIH0, xprz, xpn, t0f, t0b);
    k_gru_chunk<<<32, 512, GRU_SMEM, stream>>>(xprz, xpn, P+PO_WHH0, P+PO_BHH0, hst, h1, h1, 1, t0f, t0b);
  }

  // ---- layer 1 (+ fused FC1 accumulation) ----
  hipMemsetAsync(hst, 0, 2*256*256*sizeof(float), stream);
  hipMemsetAsync(fc1a, 0, 256*128*sizeof(float), stream);
  for (int c = 0; c < NCH; c++){
    int t0f = c * CT, t0b = (NCH - 1 - c) * CT;
    k_gemm_chunk<512><<<dim3(CROWS/128, 6, 2), 256, 0, stream>>>(h1, P+PO_WIH1, P+PO_BIH1, xprz, xpn, t0f, t0b);
    k_gru_chunk<<<32, 512, GRU_SMEM, stream>>>(xprz, xpn, P+PO_WHH1, P+PO_BHH1, hst, h2, h2b, 0, t0f, t0b);
    k_fc1_chunk<<<dim3(64, 2), 256, 0, stream>>>(h2, W1, flg+13, t0f, t0b, fc1a);
  }

  k_fc2<<<1, 256, 0, stream>>>(fc1a, P+PO_B1, P+PO_W2, P+PO_B2, flg, d_out);
}